// Round 7
// baseline (558.703 us; speedup 1.0000x reference)
//
#include <hip/hip_runtime.h>
#include <hip/hip_fp16.h>
#include <math.h>

// ---------------------------------------------------------------------------
// ADSAGE: 2x SAGEConv (mean aggr) + softmax + GCNConv, fp32.
// Aggregate-after-GEMM (mean is linear). GEMMs on matrix cores via
// split-bf16 (3-term). CSR via 2-pass radix sort by dst (R6's atomic+
// single-block-scan CSR regressed 153us: 1-block scan serialized the GPU).
// THIS REV: radix CSR restored + DEGREE-SORTED node scheduling for the
// fused gather kernels. Waves serve 16 nodes; loop time ~ max degree in
// group (Poisson(16): max-of-16 ~ 2x mean -> ~45% masked waste). perm[]
// bucket-sorts nodes by degree so each group has ~equal degrees ->
// divergence ~0. gcn_agg is 1-wave-per-node (no divergence), unpermuted.
// Gather dtypes: p8 fp8 lane-packed 6.4MB; r8 fp8 lane-packed 3.2MB;
// tp16 fp16 exact (fp8 tp failed absmax in R4).
// Pipeline:
//   p8,q16 = x @ [W1l|W1r]                        gemm1
//   r8,s16 = relu(mean(p8)+q16+b1l) @ [W2l|W2r]   FUSED pair-split, perm
//   tp16 = softmax(mean(r8)+s16+b2l) @ Wg * dinv  FUSED pair-split, perm
//   out  = dinv*(sum_j tp[j] + tp[i]) + bg        gather (half2 lanes)
// ---------------------------------------------------------------------------

typedef __attribute__((ext_vector_type(8))) short bf16x8;
typedef __attribute__((ext_vector_type(4))) float f32x4;
typedef __attribute__((ext_vector_type(2))) float f32v2;

__device__ inline unsigned short f32_bf16_hi(float f) {
    unsigned int u = __builtin_bit_cast(unsigned int, f);
    u = (u + 0x7FFFu + ((u >> 16) & 1u)) >> 16;
    return (unsigned short)u;
}
__device__ inline float bf16_to_f32(unsigned short h) {
    unsigned int u = ((unsigned int)h) << 16;
    return __builtin_bit_cast(float, u);
}

union H8 { float4 f4; __half2 h[4]; };

// decode 16 fp8 bytes (one uint4) into two 8-float accumulator slices
__device__ inline void dec16(uint4 u, float* a0, float* a1) {
    f32v2 x0 = __builtin_amdgcn_cvt_pk_f32_fp8(u.x, false);
    f32v2 x1 = __builtin_amdgcn_cvt_pk_f32_fp8(u.x, true);
    f32v2 y0 = __builtin_amdgcn_cvt_pk_f32_fp8(u.y, false);
    f32v2 y1 = __builtin_amdgcn_cvt_pk_f32_fp8(u.y, true);
    a0[0] += x0[0]; a0[1] += x0[1]; a0[2] += x1[0]; a0[3] += x1[1];
    a0[4] += y0[0]; a0[5] += y0[1]; a0[6] += y1[0]; a0[7] += y1[1];
    f32v2 z0 = __builtin_amdgcn_cvt_pk_f32_fp8(u.z, false);
    f32v2 z1 = __builtin_amdgcn_cvt_pk_f32_fp8(u.z, true);
    f32v2 w0 = __builtin_amdgcn_cvt_pk_f32_fp8(u.w, false);
    f32v2 w1 = __builtin_amdgcn_cvt_pk_f32_fp8(u.w, true);
    a1[0] += z0[0]; a1[1] += z0[1]; a1[2] += z1[0]; a1[3] += z1[1];
    a1[4] += w0[0]; a1[5] += w0[1]; a1[6] += w1[0]; a1[7] += w1[1];
}

__device__ inline unsigned char enc8(float v) {
    int w = __builtin_amdgcn_cvt_pk_fp8_f32(v, v, 0, false);
    return (unsigned char)(w & 0xff);
}

// ----------------------- radix CSR build (by dst) --------------------------
__global__ void count_kernel(const int* __restrict__ dst, int* __restrict__ off,
                             int* __restrict__ dcnt, int E, int NB, int BK) {
    __shared__ int hist[256];
    int t = threadIdx.x;
    hist[t] = 0;
    if (blockIdx.x == 0) dcnt[t] = 0;   // zero degree-histogram for perm build
    __syncthreads();
    int base = blockIdx.x * 8192;
    for (int i = t; i < 8192; i += 256) {
        int e = base + i;
        if (e < E) atomicAdd(&hist[dst[e] >> 8], 1);
    }
    __syncthreads();
    if (t < BK) off[1 + t * NB + blockIdx.x] = hist[t];
    if (blockIdx.x == 0 && t == 0) off[0] = 0;
}

__global__ void scan_reduce_kernel(const int* __restrict__ data, int* __restrict__ bsum, int n) {
    __shared__ int red[256];
    int t = threadIdx.x;
    int base = blockIdx.x * 2048 + t * 8;
    int s = 0;
    if (base + 8 <= n) {
        int4 a = *(const int4*)(data + base);
        int4 b = *(const int4*)(data + base + 4);
        s = a.x + a.y + a.z + a.w + b.x + b.y + b.z + b.w;
    } else {
        for (int i = 0; i < 8; ++i)
            if (base + i < n) s += data[base + i];
    }
    red[t] = s;
    __syncthreads();
    for (int off = 128; off > 0; off >>= 1) {
        if (t < off) red[t] += red[t + off];
        __syncthreads();
    }
    if (t == 0) bsum[blockIdx.x] = red[0];
}

__global__ void scan_offsets_kernel(int* __restrict__ bsum, int B) {
    if (threadIdx.x == 0 && blockIdx.x == 0) {
        int run = 0;
        for (int i = 0; i < B; ++i) { int v = bsum[i]; bsum[i] = run; run += v; }
    }
}

__global__ void scan_final_kernel(int* __restrict__ data, const int* __restrict__ bsum, int n) {
    __shared__ int tsum[256];
    int t = threadIdx.x;
    int base = blockIdx.x * 2048 + t * 8;
    int v[8];
    int s = 0;
#pragma unroll
    for (int i = 0; i < 8; ++i) {
        v[i] = (base + i < n) ? data[base + i] : 0;
        s += v[i];
    }
    tsum[t] = s;
    for (int off = 1; off < 256; off <<= 1) {
        __syncthreads();
        int u = (t >= off) ? tsum[t - off] : 0;
        __syncthreads();
        tsum[t] += u;
    }
    __syncthreads();
    int run = bsum[blockIdx.x] + tsum[t] - s;
#pragma unroll
    for (int i = 0; i < 8; ++i) {
        run += v[i];
        if (base + i < n) data[base + i] = run;
    }
}

__global__ void partition_kernel(const int* __restrict__ src, const int* __restrict__ dst,
                                 const int* __restrict__ off, unsigned* __restrict__ ebuf,
                                 int E, int NB, int BK) {
    __shared__ int cur[256];
    int t = threadIdx.x;
    if (t < BK) cur[t] = off[t * NB + blockIdx.x];
    __syncthreads();
    int base = blockIdx.x * 8192;
    for (int i = t; i < 8192; i += 256) {
        int e = base + i;
        if (e < E) {
            int d = dst[e];
            int pos = atomicAdd(&cur[d >> 8], 1);
            ebuf[pos] = ((unsigned)src[e] << 8) | (unsigned)(d & 255);
        }
    }
}

__global__ void finalize_kernel(const unsigned* __restrict__ ebuf, const int* __restrict__ off,
                                int* __restrict__ col, int* __restrict__ rowptr,
                                float* __restrict__ dinv, int* __restrict__ deg,
                                int* __restrict__ dcnt, int N, int NB, int E) {
    __shared__ int hist[256], scn[256], cur[256];
    int b = blockIdx.x, t = threadIdx.x;
    int base = off[b * NB];
    int end  = off[(b + 1) * NB];
    int M = end - base;
    hist[t] = 0;
    __syncthreads();
    for (int i = t; i < M; i += 256) atomicAdd(&hist[ebuf[base + i] & 255u], 1);
    __syncthreads();
    scn[t] = hist[t];
    for (int o = 1; o < 256; o <<= 1) {
        __syncthreads();
        int u = (t >= o) ? scn[t - o] : 0;
        __syncthreads();
        scn[t] += u;
    }
    __syncthreads();
    int excl = scn[t] - hist[t];
    int node = b * 256 + t;
    if (node < N) {
        rowptr[node] = base + excl;
        dinv[node] = rsqrtf((float)(hist[t] + 1));
        int d = hist[t];
        deg[node] = d;
        atomicAdd(&dcnt[d < 255 ? d : 255], 1);   // degree histogram for perm
    }
    if (b == 0 && t == 0) rowptr[N] = E;
    cur[t] = base + excl;
    __syncthreads();
    for (int i = t; i < M; i += 256) {
        unsigned w = ebuf[base + i];
        int pos = atomicAdd(&cur[w & 255u], 1);
        col[pos] = (int)(w >> 8);
    }
}

// ----------------- degree-sort permutation (bucket sort) -------------------
__global__ void perm_scan_kernel(int* __restrict__ dcnt) {
    __shared__ int s[256];
    int t = threadIdx.x;
    int v = dcnt[t];
    s[t] = v;
    for (int o = 1; o < 256; o <<= 1) {
        __syncthreads();
        int u = (t >= o) ? s[t - o] : 0;
        __syncthreads();
        s[t] += u;
    }
    __syncthreads();
    dcnt[t] = s[t] - v;   // exclusive prefix = bucket base (reused as cursor)
}

__global__ void perm_scatter_kernel(const int* __restrict__ deg, int* __restrict__ dcnt,
                                    int* __restrict__ perm, int N) {
    int i = blockIdx.x * 256 + threadIdx.x;
    if (i < N) {
        int d = deg[i];
        if (d > 255) d = 255;
        int pos = atomicAdd(&dcnt[d], 1);
        perm[pos] = i;
    }
}

// -------------------------- weight pre-pack --------------------------------
__global__ void packw_kernel(const float* __restrict__ W1l, const float* __restrict__ W1r,
                             const float* __restrict__ W2l, const float* __restrict__ W2r,
                             const float* __restrict__ Wg,
                             unsigned short* __restrict__ p1h, unsigned short* __restrict__ p1l,
                             unsigned short* __restrict__ p2h, unsigned short* __restrict__ p2l,
                             unsigned short* __restrict__ p3h, unsigned short* __restrict__ p3l) {
    int which = blockIdx.y;
    const float* W;
    unsigned short *hi, *lo;
    int K, Mp, colOff, T;
    if (which == 0)      { W = W1l; hi = p1h; lo = p1l; K = 128; Mp = 128; colOff = 0;   T = 16; }
    else if (which == 1) { W = W1r; hi = p1h; lo = p1l; K = 128; Mp = 128; colOff = 128; T = 16; }
    else if (which == 2) { W = W2l; hi = p2h; lo = p2l; K = 128; Mp = 64;  colOff = 0;   T = 8;  }
    else if (which == 3) { W = W2r; hi = p2h; lo = p2l; K = 128; Mp = 64;  colOff = 64;  T = 8;  }
    else                 { W = Wg;  hi = p3h; lo = p3l; K = 64;  Mp = 64;  colOff = 0;   T = 4;  }
    int idx = blockIdx.x * blockDim.x + threadIdx.x;
    if (idx >= K * Mp) return;
    int k = idx / Mp, m = idx % Mp;
    float w = W[(size_t)k * Mp + m];
    int colI = colOff + m;
    int s = k >> 5, kk = k & 31, qq = kk >> 3, j = kk & 7;
    int tt = colI >> 4, n = colI & 15;
    int lane = qq * 16 + n;
    size_t pos = ((size_t)(s * T + tt) * 64 + lane) * 8 + j;
    unsigned short h = f32_bf16_hi(w);
    hi[pos] = h;
    lo[pos] = f32_bf16_hi(w - bf16_to_f32(h));
}

// --------------------------- gemm1 (K=128, M=256) --------------------------
// A-loads hoisted. y=0 -> p8 (fp8 e4m3, LANE-PACKED: byte pos(f) =
// ((f>>3)&3)*32 + (f>>5)*8 + (f&7)), y=1 -> q16 (fp16).
__launch_bounds__(256)
__global__ void gemm1_kernel(const float* __restrict__ A,
                             const unsigned short* __restrict__ Whi,
                             const unsigned short* __restrict__ Wlo,
                             unsigned char* __restrict__ outA8, __half* __restrict__ outB, int N) {
    constexpr int Ttot = 16, TB = 8;
    __shared__ __align__(16) unsigned char pk[4][16][128];
    const int lane = threadIdx.x & 63;
    const int wave = threadIdx.x >> 6;
    const int m = lane & 15, q = lane >> 4;
    const int t0 = blockIdx.y * TB;
    const int row0 = blockIdx.x * 64 + wave * 16;
    int arow = row0 + m;
    if (arow >= N) arow = N - 1;
    const float* ap = A + (size_t)arow * 128 + q * 8;

    float av[4][8];
#pragma unroll
    for (int s = 0; s < 4; ++s) {
        *(float4*)(av[s])     = *(const float4*)(ap + s * 32);
        *(float4*)(av[s] + 4) = *(const float4*)(ap + s * 32 + 4);
    }
    bf16x8 ahi[4], alo[4];
#pragma unroll
    for (int s = 0; s < 4; ++s)
#pragma unroll
        for (int i = 0; i < 8; ++i) {
            unsigned short h = f32_bf16_hi(av[s][i]);
            ahi[s][i] = (short)h;
            alo[s][i] = (short)f32_bf16_hi(av[s][i] - bf16_to_f32(h));
        }

    f32x4 acc[TB];
#pragma unroll
    for (int t = 0; t < TB; ++t) acc[t] = (f32x4)(0.f);
    const bf16x8* whp = (const bf16x8*)Whi;
    const bf16x8* wlp = (const bf16x8*)Wlo;
#pragma unroll
    for (int s = 0; s < 4; ++s) {
        const int base = (s * Ttot + t0) * 64 + lane;
#pragma unroll
        for (int t = 0; t < TB; ++t) {
            bf16x8 wh = whp[base + t * 64];
            bf16x8 wl = wlp[base + t * 64];
            acc[t] = __builtin_amdgcn_mfma_f32_16x16x32_bf16(ahi[s], wh, acc[t], 0, 0, 0);
            acc[t] = __builtin_amdgcn_mfma_f32_16x16x32_bf16(alo[s], wh, acc[t], 0, 0, 0);
            acc[t] = __builtin_amdgcn_mfma_f32_16x16x32_bf16(ahi[s], wl, acc[t], 0, 0, 0);
        }
    }

    if (blockIdx.y == 0) {
#pragma unroll
        for (int r = 0; r < 4; ++r) {
            int row = q * 4 + r;
            int sw = (row & 3) << 5;
#pragma unroll
            for (int t = 0; t < 8; t += 2) {
                int w = __builtin_amdgcn_cvt_pk_fp8_f32(acc[t][r], acc[t + 1][r], 0, false);
                int off = (t >> 1) * 8 + (m & 7);
                int c0 = ((2 * t + (m >> 3)) & 3) * 32 + off;
                int c1 = ((2 * t + 2 + (m >> 3)) & 3) * 32 + off;
                pk[wave][row][c0 ^ sw] = (unsigned char)(w & 0xff);
                pk[wave][row][c1 ^ sw] = (unsigned char)((w >> 8) & 0xff);
            }
        }
        __syncthreads();
        int rr = lane >> 2, qt = lane & 3;
        int grow = row0 + rr;
        if (grow < N) {
            const unsigned char* srcp = &pk[wave][rr][(qt ^ (rr & 3)) * 32];
            uint4 v0 = *(const uint4*)(srcp);
            uint4 v1 = *(const uint4*)(srcp + 16);
            *(uint4*)(outA8 + (size_t)grow * 128 + qt * 32) = v0;
            *(uint4*)(outA8 + (size_t)grow * 128 + qt * 32 + 16) = v1;
        }
    } else {
#pragma unroll
        for (int r = 0; r < 4; ++r) {
            int row = row0 + q * 4 + r;
            if (row < N) {
#pragma unroll
                for (int t = 0; t < TB; ++t) {
                    int c = (t0 + t) * 16 + m - 128;
                    outB[(size_t)row * 128 + c] = __float2half(acc[t][r]);
                }
            }
        }
    }
}

// ------------------- FUSED: agg1+relu+gemm2 (K=128) ------------------------
// Pair-split, 32 perm-slots/block; nodes taken from degree-sorted perm[] so
// each 16-node group has ~equal degree (divergence ~0). Lane-packed p8
// gather (2 x uint4/lane/edge). Wave 0 writes r8 (fp8), wave 1 writes s16.
__launch_bounds__(256)
__global__ void sage2_fused_kernel(const unsigned char* __restrict__ p8, const __half* __restrict__ q16,
                                   const int* __restrict__ rowptr, const int* __restrict__ col,
                                   const int* __restrict__ perm,
                                   const float* __restrict__ b1l,
                                   const unsigned short* __restrict__ Whi,
                                   const unsigned short* __restrict__ Wlo,
                                   unsigned char* __restrict__ r8, __half* __restrict__ s16, int N) {
    __shared__ float part[4][64][16];
    const int lane = threadIdx.x & 63;
    const int wave = threadIdx.x >> 6;
    const int pairH = wave & 1;
    const int grp   = wave >> 1;
    const int m = lane & 15, q = lane >> 4;
    const int row0 = blockIdx.x * 32 + grp * 16;
    int prow = row0 + m;
    int node = perm[(prow < N) ? prow : (N - 1)];
    int sAll = rowptr[node];
    int eAll = (prow < N) ? rowptr[node + 1] : sAll;
    int deg  = eAll - sAll;
    int half0 = (deg + 1) >> 1;
    int sIdx = sAll + (pairH ? half0 : 0);
    int eIdx = pairH ? eAll : (sAll + half0);

    float acc[4][8];
#pragma unroll
    for (int s = 0; s < 4; ++s)
#pragma unroll
        for (int i = 0; i < 8; ++i) acc[s][i] = 0.f;

    const unsigned char* pb = p8 + q * 32;
    int ptr = sIdx;
    for (; ptr + 4 <= eIdx; ptr += 4) {
        int j0 = col[ptr], j1 = col[ptr + 1], j2 = col[ptr + 2], j3 = col[ptr + 3];
        uint4 uA[4], uB[4];
        uA[0] = *(const uint4*)(pb + (size_t)j0 * 128);
        uB[0] = *(const uint4*)(pb + (size_t)j0 * 128 + 16);
        uA[1] = *(const uint4*)(pb + (size_t)j1 * 128);
        uB[1] = *(const uint4*)(pb + (size_t)j1 * 128 + 16);
        uA[2] = *(const uint4*)(pb + (size_t)j2 * 128);
        uB[2] = *(const uint4*)(pb + (size_t)j2 * 128 + 16);
        uA[3] = *(const uint4*)(pb + (size_t)j3 * 128);
        uB[3] = *(const uint4*)(pb + (size_t)j3 * 128 + 16);
#pragma unroll
        for (int e = 0; e < 4; ++e) {
            dec16(uA[e], acc[0], acc[1]);
            dec16(uB[e], acc[2], acc[3]);
        }
    }
    for (; ptr < eIdx; ++ptr) {
        int j0 = col[ptr];
        uint4 uA = *(const uint4*)(pb + (size_t)j0 * 128);
        uint4 uB = *(const uint4*)(pb + (size_t)j0 * 128 + 16);
        dec16(uA, acc[0], acc[1]);
        dec16(uB, acc[2], acc[3]);
    }

    // cross-wave combine: two chunks of 4 float4 slots each, XOR-swizzled
    float* ap = &acc[0][0];
    const int swz = lane & 3;
#pragma unroll
    for (int c = 0; c < 2; ++c) {
        if (c) __syncthreads();
#pragma unroll
        for (int sl = 0; sl < 4; ++sl)
            *(float4*)&part[wave][lane][(sl ^ swz) * 4] =
                *(const float4*)(ap + (c * 4 + sl) * 4);
        __syncthreads();
#pragma unroll
        for (int sl = 0; sl < 4; ++sl) {
            float4 pv = *(const float4*)&part[wave ^ 1][lane][(sl ^ swz) * 4];
            int g = (c * 4 + sl) * 4;
            ap[g]     += pv.x;
            ap[g + 1] += pv.y;
            ap[g + 2] += pv.z;
            ap[g + 3] += pv.w;
        }
    }

    float inv = 1.0f / fmaxf((float)deg, 1.0f);
    bf16x8 ahi[4], alo[4];
#pragma unroll
    for (int s = 0; s < 4; ++s) {
        H8 qv;
        qv.f4 = *(const float4*)(q16 + (size_t)node * 128 + s * 32 + q * 8);
        float bv[8];
        *(float4*)(bv)     = *(const float4*)(b1l + s * 32 + q * 8);
        *(float4*)(bv + 4) = *(const float4*)(b1l + s * 32 + q * 8 + 4);
#pragma unroll
        for (int i = 0; i < 8; ++i) {
            float qf = __half2float(((const __half*)&qv)[i]);
            float h = fmaxf(acc[s][i] * inv + qf + bv[i], 0.f);
            unsigned short hb = f32_bf16_hi(h);
            ahi[s][i] = (short)hb;
            alo[s][i] = (short)f32_bf16_hi(h - bf16_to_f32(hb));
        }
    }

    // MFMA: this wave computes tiles tg = pairH*4 + t (t=0..3)
    f32x4 accm[4];
#pragma unroll
    for (int t = 0; t < 4; ++t) accm[t] = (f32x4)(0.f);
    const bf16x8* whp = (const bf16x8*)Whi;
    const bf16x8* wlp = (const bf16x8*)Wlo;
#pragma unroll
    for (int s = 0; s < 4; ++s) {
        const int base = (s * 8 + pairH * 4) * 64 + lane;
#pragma unroll
        for (int t = 0; t < 4; ++t) {
            bf16x8 wh = whp[base + t * 64];
            bf16x8 wl = wlp[base + t * 64];
            accm[t] = __builtin_amdgcn_mfma_f32_16x16x32_bf16(ahi[s], wh, accm[t], 0, 0, 0);
            accm[t] = __builtin_amdgcn_mfma_f32_16x16x32_bf16(alo[s], wh, accm[t], 0, 0, 0);
            accm[t] = __builtin_amdgcn_mfma_f32_16x16x32_bf16(ahi[s], wl, accm[t], 0, 0, 0);
        }
    }
#pragma unroll
    for (int r = 0; r < 4; ++r) {
        int ridx = row0 + q * 4 + r;
        if (ridx < N) {
            int onode = __shfl(node, q * 4 + r, 64);   // node of output row
            if (pairH == 0) {
                // r8: fp8 bytes at lane-packed pos(c) = ((c>>3)&3)*16 + (c>>5)*8 + (c&7)
#pragma unroll
                for (int t = 0; t < 4; ++t) {
                    int c = t * 16 + m;
                    int pos = ((c >> 3) & 3) * 16 + ((c >> 5) & 1) * 8 + (c & 7);
                    r8[(size_t)onode * 64 + pos] = enc8(accm[t][r]);
                }
            } else {
#pragma unroll
                for (int t = 0; t < 4; ++t) {
                    int c = t * 16 + m;
                    s16[(size_t)onode * 64 + c] = __float2half(accm[t][r]);
                }
            }
        }
    }
}

// --------------- FUSED: agg2+softmax+gemm3 (K=64, dinv scale) --------------
// Pair-split, degree-sorted perm; lane-packed r8 gather (1 uint4/lane/edge).
// Single fp16 tp16 output (N x 64).
__launch_bounds__(256)
__global__ void gcn_prep_fused_kernel(const unsigned char* __restrict__ r8, const __half* __restrict__ s16,
                                      const int* __restrict__ rowptr, const int* __restrict__ col,
                                      const int* __restrict__ perm,
                                      const float* __restrict__ b2l,
                                      const unsigned short* __restrict__ Whi,
                                      const unsigned short* __restrict__ Wlo,
                                      const float* __restrict__ dinv,
                                      __half* __restrict__ tp16, int N) {
    __shared__ float part[4][64][16];
    const int lane = threadIdx.x & 63;
    const int wave = threadIdx.x >> 6;
    const int pairH = wave & 1;
    const int grp   = wave >> 1;
    const int m = lane & 15, q = lane >> 4;
    const int row0 = blockIdx.x * 32 + grp * 16;
    int prow = row0 + m;
    int node = perm[(prow < N) ? prow : (N - 1)];
    int sAll = rowptr[node];
    int eAll = (prow < N) ? rowptr[node + 1] : sAll;
    int deg  = eAll - sAll;
    int half0 = (deg + 1) >> 1;
    int sIdx = sAll + (pairH ? half0 : 0);
    int eIdx = pairH ? eAll : (sAll + half0);

    float acc[2][8];
#pragma unroll
    for (int s = 0; s < 2; ++s)
#pragma unroll
        for (int i = 0; i < 8; ++i) acc[s][i] = 0.f;

    const unsigned char* rb = r8 + q * 16;
    int ptr = sIdx;
    for (; ptr + 4 <= eIdx; ptr += 4) {
        int j0 = col[ptr], j1 = col[ptr + 1], j2 = col[ptr + 2], j3 = col[ptr + 3];
        uint4 u0 = *(const uint4*)(rb + (size_t)j0 * 64);
        uint4 u1 = *(const uint4*)(rb + (size_t)j1 * 64);
        uint4 u2 = *(const uint4*)(rb + (size_t)j2 * 64);
        uint4 u3 = *(const uint4*)(rb + (size_t)j3 * 64);
        dec16(u0, acc[0], acc[1]);
        dec16(u1, acc[0], acc[1]);
        dec16(u2, acc[0], acc[1]);
        dec16(u3, acc[0], acc[1]);
    }
    for (; ptr < eIdx; ++ptr) {
        int j0 = col[ptr];
        uint4 u0 = *(const uint4*)(rb + (size_t)j0 * 64);
        dec16(u0, acc[0], acc[1]);
    }

    // cross-wave combine: single chunk (4 float4 slots), XOR-swizzled
    float* ap = &acc[0][0];
    const int swz = lane & 3;
#pragma unroll
    for (int sl = 0; sl < 4; ++sl)
        *(float4*)&part[wave][lane][(sl ^ swz) * 4] = *(const float4*)(ap + sl * 4);
    __syncthreads();
#pragma unroll
    for (int sl = 0; sl < 4; ++sl) {
        float4 pv = *(const float4*)&part[wave ^ 1][lane][(sl ^ swz) * 4];
        ap[sl * 4]     += pv.x;
        ap[sl * 4 + 1] += pv.y;
        ap[sl * 4 + 2] += pv.z;
        ap[sl * 4 + 3] += pv.w;
    }

    float inv = 1.0f / fmaxf((float)deg, 1.0f);
    float v[2][8];
    float mx = -1e30f;
#pragma unroll
    for (int s = 0; s < 2; ++s) {
        H8 sv;
        sv.f4 = *(const float4*)(s16 + (size_t)node * 64 + s * 32 + q * 8);
        float bv[8];
        *(float4*)(bv)     = *(const float4*)(b2l + s * 32 + q * 8);
        *(float4*)(bv + 4) = *(const float4*)(b2l + s * 32 + q * 8 + 4);
#pragma unroll
        for (int i = 0; i < 8; ++i) {
            float sf = __half2float(((const __half*)&sv)[i]);
            v[s][i] = acc[s][i] * inv + sf + bv[i];
            mx = fmaxf(mx, v[s][i]);
        }
    }
    mx = fmaxf(mx, __shfl_xor(mx, 16, 64));
    mx = fmaxf(mx, __shfl_xor(mx, 32, 64));
    float sm = 0.f;
#pragma unroll
    for (int s = 0; s < 2; ++s)
#pragma unroll
        for (int i = 0; i < 8; ++i) {
            v[s][i] = expf(v[s][i] - mx);
            sm += v[s][i];
        }
    sm += __shfl_xor(sm, 16, 64);
    sm += __shfl_xor(sm, 32, 64);
    float is = 1.0f / sm;

    bf16x8 ahi[2], alo[2];
#pragma unroll
    for (int s = 0; s < 2; ++s)
#pragma unroll
        for (int i = 0; i < 8; ++i) {
            float h = v[s][i] * is;
            unsigned short hb = f32_bf16_hi(h);
            ahi[s][i] = (short)hb;
            alo[s][i] = (short)f32_bf16_hi(h - bf16_to_f32(hb));
        }

    // MFMA: this wave computes tiles tg = pairH*2 + t (t=0..1)
    f32x4 accm[2];
#pragma unroll
    for (int t = 0; t < 2; ++t) accm[t] = (f32x4)(0.f);
    const bf16x8* whp = (const bf16x8*)Whi;
    const bf16x8* wlp = (const bf16x8*)Wlo;
#pragma unroll
    for (int s = 0; s < 2; ++s) {
        const int base = (s * 4 + pairH * 2) * 64 + lane;
#pragma unroll
        for (int t = 0; t < 2; ++t) {
            bf16x8 wh = whp[base + t * 64];
            bf16x8 wl = wlp[base + t * 64];
            accm[t] = __builtin_amdgcn_mfma_f32_16x16x32_bf16(ahi[s], wh, accm[t], 0, 0, 0);
            accm[t] = __builtin_amdgcn_mfma_f32_16x16x32_bf16(alo[s], wh, accm[t], 0, 0, 0);
            accm[t] = __builtin_amdgcn_mfma_f32_16x16x32_bf16(ahi[s], wl, accm[t], 0, 0, 0);
        }
    }
#pragma unroll
    for (int r = 0; r < 4; ++r) {
        int ridx = row0 + q * 4 + r;
        if (ridx < N) {
            int onode = __shfl(node, q * 4 + r, 64);
            float sc = dinv[onode];
#pragma unroll
            for (int t = 0; t < 2; ++t) {
                int c = (pairH * 2 + t) * 16 + m;
                tp16[(size_t)onode * 64 + c] = __float2half(accm[t][r] * sc);
            }
        }
    }
}

// ------------------------------ gcn gather ---------------------------------
// half2 lanes: 32 feature-pair lanes x 2 edge-parity groups; combine via
// shfl_xor(32). One wave per node -> no inter-node divergence (no perm).
__global__ void gcn_agg_kernel(const __half* __restrict__ tp,
                               const int* __restrict__ rowptr, const int* __restrict__ col,
                               const float* __restrict__ dinv, const float* __restrict__ bg,
                               float* __restrict__ out, int N) {
    int node = blockIdx.x * 4 + (threadIdx.x >> 6);
    if (node >= N) return;
    int lane = threadIdx.x & 63;
    int f2 = lane & 31;   // features 2*f2, 2*f2+1
    int ep = lane >> 5;   // edge parity
    int s = rowptr[node], e = rowptr[node + 1];
    float ax[8], ay[8];
#pragma unroll
    for (int k = 0; k < 8; ++k) { ax[k] = 0.f; ay[k] = 0.f; }
    int p = s;
    for (; p + 16 <= e; p += 16) {
#pragma unroll
        for (int k = 0; k < 8; ++k) {
            int j = col[p + 2 * k + ep];
            float2 f = __half22float2(*(const __half2*)(tp + (size_t)j * 64 + 2 * f2));
            ax[k] += f.x;
            ay[k] += f.y;
        }
    }
    for (int t = p + ep; t < e; t += 2) {
        int j = col[t];
        float2 f = __half22float2(*(const __half2*)(tp + (size_t)j * 64 + 2 * f2));
        ax[0] += f.x;
        ay[0] += f.y;
    }
    float sx = ((ax[0] + ax[1]) + (ax[2] + ax[3])) + ((ax[4] + ax[5]) + (ax[6] + ax[7]));
    float sy = ((ay[0] + ay[1]) + (ay[2] + ay[3])) + ((ay[4] + ay[5]) + (ay[6] + ay[7]));
    sx += __shfl_xor(sx, 32, 64);
    sy += __shfl_xor(sy, 32, 64);
    if (ep == 0) {
        float2 selfv = __half22float2(*(const __half2*)(tp + (size_t)node * 64 + 2 * f2));
        float di = dinv[node];
        float2 o;
        o.x = (sx + selfv.x) * di + bg[2 * f2];
        o.y = (sy + selfv.y) * di + bg[2 * f2 + 1];
        *(float2*)(out + (size_t)node * 64 + 2 * f2) = o;
    }
}

extern "C" void kernel_launch(void* const* d_in, const int* in_sizes, int n_in,
                              void* d_out, int out_size, void* d_ws, size_t ws_size,
                              hipStream_t stream) {
    const float* x = (const float*)d_in[0];
    const int* ei = (const int*)d_in[1];    // int32 per harness conversion
    const float* W1l = (const float*)d_in[2];
    const float* b1l = (const float*)d_in[3];
    const float* W1r = (const float*)d_in[4];
    const float* W2l = (const float*)d_in[5];
    const float* b2l = (const float*)d_in[6];
    const float* W2r = (const float*)d_in[7];
    const float* Wg  = (const float*)d_in[8];
    const float* bg  = (const float*)d_in[9];

    const int N = in_sizes[0] / 128;
    const int E = in_sizes[1] / 2;
    const int* srcp = ei;
    const int* dstp = ei + E;

    const int NB = (E + 8191) / 8192;
    const int BK = (N + 255) >> 8;
    const int len = BK * NB;

    // workspace layout
    float* ws = (float*)d_ws;
    float* dinv = ws;                              // N
    unsigned char* p8 = (unsigned char*)(dinv + N);   // N*128 B (fp8)
    __half* q16 = (__half*)(p8 + (size_t)N * 128);    // N*128 half
    unsigned char* r8 = (unsigned char*)(q16 + (size_t)N * 128); // N*64 B (fp8)
    __half* s16 = (__half*)(r8 + (size_t)N * 64);     // N*64 half
    __half* tp16 = s16 + (size_t)N * 64;              // N*64 half
    int* rowptr = (int*)(tp16 + (size_t)N * 64);   // N+1
    int* off    = rowptr + (N + 1);                // len+2
    int* colbuf = off + len + 2;                   // E
    unsigned* ebuf = (unsigned*)(colbuf + E);      // E
    int* bsum   = (int*)(ebuf + E);                // 32
    int* deg    = bsum + 32;                       // N
    int* dcnt   = deg + N;                         // 256
    int* perm   = dcnt + 256;                      // N
    uintptr_t up = (uintptr_t)(perm + N);
    up = (up + 15) & ~(uintptr_t)15;
    unsigned short* p1h = (unsigned short*)up;     // 32768 (128x256)
    unsigned short* p1l = p1h + 32768;
    unsigned short* p2h = p1l + 32768;             // 16384 (128x128)
    unsigned short* p2l = p2h + 16384;
    unsigned short* p3h = p2l + 16384;             // 4096 (64x64)
    unsigned short* p3l = p3h + 4096;

    float* out = (float*)d_out;

    // --- CSR build (radix by dst) + degree histogram ---
    count_kernel<<<NB, 256, 0, stream>>>(dstp, off, dcnt, E, NB, BK);
    const int sn = len + 1;
    const int SBs = (sn + 2047) / 2048;
    scan_reduce_kernel<<<SBs, 256, 0, stream>>>(off, bsum, sn);
    scan_offsets_kernel<<<1, 64, 0, stream>>>(bsum, SBs);
    scan_final_kernel<<<SBs, 256, 0, stream>>>(off, bsum, sn);
    partition_kernel<<<NB, 256, 0, stream>>>(srcp, dstp, off, ebuf, E, NB, BK);
    finalize_kernel<<<BK, 256, 0, stream>>>(ebuf, off, colbuf, rowptr, dinv,
                                            deg, dcnt, N, NB, E);

    // --- degree-sort permutation ---
    perm_scan_kernel<<<1, 256, 0, stream>>>(dcnt);
    perm_scatter_kernel<<<(N + 255) / 256, 256, 0, stream>>>(deg, dcnt, perm, N);

    packw_kernel<<<dim3(64, 5), 256, 0, stream>>>(W1l, W1r, W2l, W2r, Wg,
                                                  p1h, p1l, p2h, p2l, p3h, p3l);

    const int gb  = (N + 63) / 64;   // gemm1
    const int gbf = (N + 31) / 32;   // fused (pair-split)
    const int ab  = (N + 3) / 4;     // gcn_agg

    // gemm1: y=0 -> p8 (fp8, lane-packed), y=1 -> q16 (fp16)
    gemm1_kernel<<<dim3(gb, 2), 256, 0, stream>>>(x, p1h, p1l, p8, q16, N);

    // fused: h1 = relu(mean(p8)+q16+b1l); [r8|s16] = h1 @ [W2l|W2r]
    sage2_fused_kernel<<<gbf, 256, 0, stream>>>(p8, q16, rowptr, colbuf, perm, b1l,
                                                p2h, p2l, r8, s16, N);

    // fused: h2 = softmax(mean(r8)+s16+b2l); tp16 = (h2 @ Wg) * dinv
    gcn_prep_fused_kernel<<<gbf, 256, 0, stream>>>(r8, s16, rowptr, colbuf, perm, b2l,
                                                   p3h, p3l, dinv, tp16, N);

    gcn_agg_kernel<<<ab, 256, 0, stream>>>(tp16, rowptr, colbuf, dinv, bg, out, N);
}

// Round 8
// 273.514 us; speedup vs baseline: 2.0427x; 2.0427x over previous
//
#include <hip/hip_runtime.h>
#include <hip/hip_fp16.h>
#include <math.h>

// ---------------------------------------------------------------------------
// ADSAGE: 2x SAGEConv (mean aggr) + softmax + GCNConv, fp32.
// Aggregate-after-GEMM (mean is linear). GEMMs on matrix cores via
// split-bf16 (3-term). CSR via 2-pass radix sort by dst.
// THIS REV: R7's degree-sort experiment was destroyed by per-node global
// atomics into ~35 hot degree buckets (finalize 15->158us, scatter similar).
// Permutation now built with BLOCK-AGGREGATED atomics (LDS histogram ->
// <=1 global atomic per bin per block; range-reservation scatter). The
// fused kernels are byte-identical to R7 -> clean A/B on degree-sorting.
// Gather dtypes: p8 fp8 lane-packed 6.4MB; r8 fp8 lane-packed 3.2MB;
// tp16 fp16 exact (fp8 tp failed absmax in R4).
// Pipeline:
//   p8,q16 = x @ [W1l|W1r]                        gemm1
//   r8,s16 = relu(mean(p8)+q16+b1l) @ [W2l|W2r]   FUSED pair-split, perm
//   tp16 = softmax(mean(r8)+s16+b2l) @ Wg * dinv  FUSED pair-split, perm
//   out  = dinv*(sum_j tp[j] + tp[i]) + bg        gather (half2 lanes)
// ---------------------------------------------------------------------------

typedef __attribute__((ext_vector_type(8))) short bf16x8;
typedef __attribute__((ext_vector_type(4))) float f32x4;
typedef __attribute__((ext_vector_type(2))) float f32v2;

__device__ inline unsigned short f32_bf16_hi(float f) {
    unsigned int u = __builtin_bit_cast(unsigned int, f);
    u = (u + 0x7FFFu + ((u >> 16) & 1u)) >> 16;
    return (unsigned short)u;
}
__device__ inline float bf16_to_f32(unsigned short h) {
    unsigned int u = ((unsigned int)h) << 16;
    return __builtin_bit_cast(float, u);
}

union H8 { float4 f4; __half2 h[4]; };

// decode 16 fp8 bytes (one uint4) into two 8-float accumulator slices
__device__ inline void dec16(uint4 u, float* a0, float* a1) {
    f32v2 x0 = __builtin_amdgcn_cvt_pk_f32_fp8(u.x, false);
    f32v2 x1 = __builtin_amdgcn_cvt_pk_f32_fp8(u.x, true);
    f32v2 y0 = __builtin_amdgcn_cvt_pk_f32_fp8(u.y, false);
    f32v2 y1 = __builtin_amdgcn_cvt_pk_f32_fp8(u.y, true);
    a0[0] += x0[0]; a0[1] += x0[1]; a0[2] += x1[0]; a0[3] += x1[1];
    a0[4] += y0[0]; a0[5] += y0[1]; a0[6] += y1[0]; a0[7] += y1[1];
    f32v2 z0 = __builtin_amdgcn_cvt_pk_f32_fp8(u.z, false);
    f32v2 z1 = __builtin_amdgcn_cvt_pk_f32_fp8(u.z, true);
    f32v2 w0 = __builtin_amdgcn_cvt_pk_f32_fp8(u.w, false);
    f32v2 w1 = __builtin_amdgcn_cvt_pk_f32_fp8(u.w, true);
    a1[0] += z0[0]; a1[1] += z0[1]; a1[2] += z1[0]; a1[3] += z1[1];
    a1[4] += w0[0]; a1[5] += w0[1]; a1[6] += w1[0]; a1[7] += w1[1];
}

__device__ inline unsigned char enc8(float v) {
    int w = __builtin_amdgcn_cvt_pk_fp8_f32(v, v, 0, false);
    return (unsigned char)(w & 0xff);
}

// ----------------------- radix CSR build (by dst) --------------------------
__global__ void count_kernel(const int* __restrict__ dst, int* __restrict__ off,
                             int* __restrict__ dcnt, int E, int NB, int BK) {
    __shared__ int hist[256];
    int t = threadIdx.x;
    hist[t] = 0;
    if (blockIdx.x == 0) dcnt[t] = 0;   // zero degree-histogram bins
    __syncthreads();
    int base = blockIdx.x * 8192;
    for (int i = t; i < 8192; i += 256) {
        int e = base + i;
        if (e < E) atomicAdd(&hist[dst[e] >> 8], 1);
    }
    __syncthreads();
    if (t < BK) off[1 + t * NB + blockIdx.x] = hist[t];
    if (blockIdx.x == 0 && t == 0) off[0] = 0;
}

__global__ void scan_reduce_kernel(const int* __restrict__ data, int* __restrict__ bsum, int n) {
    __shared__ int red[256];
    int t = threadIdx.x;
    int base = blockIdx.x * 2048 + t * 8;
    int s = 0;
    if (base + 8 <= n) {
        int4 a = *(const int4*)(data + base);
        int4 b = *(const int4*)(data + base + 4);
        s = a.x + a.y + a.z + a.w + b.x + b.y + b.z + b.w;
    } else {
        for (int i = 0; i < 8; ++i)
            if (base + i < n) s += data[base + i];
    }
    red[t] = s;
    __syncthreads();
    for (int off = 128; off > 0; off >>= 1) {
        if (t < off) red[t] += red[t + off];
        __syncthreads();
    }
    if (t == 0) bsum[blockIdx.x] = red[0];
}

__global__ void scan_offsets_kernel(int* __restrict__ bsum, int B) {
    if (threadIdx.x == 0 && blockIdx.x == 0) {
        int run = 0;
        for (int i = 0; i < B; ++i) { int v = bsum[i]; bsum[i] = run; run += v; }
    }
}

__global__ void scan_final_kernel(int* __restrict__ data, const int* __restrict__ bsum, int n) {
    __shared__ int tsum[256];
    int t = threadIdx.x;
    int base = blockIdx.x * 2048 + t * 8;
    int v[8];
    int s = 0;
#pragma unroll
    for (int i = 0; i < 8; ++i) {
        v[i] = (base + i < n) ? data[base + i] : 0;
        s += v[i];
    }
    tsum[t] = s;
    for (int off = 1; off < 256; off <<= 1) {
        __syncthreads();
        int u = (t >= off) ? tsum[t - off] : 0;
        __syncthreads();
        tsum[t] += u;
    }
    __syncthreads();
    int run = bsum[blockIdx.x] + tsum[t] - s;
#pragma unroll
    for (int i = 0; i < 8; ++i) {
        run += v[i];
        if (base + i < n) data[base + i] = run;
    }
}

__global__ void partition_kernel(const int* __restrict__ src, const int* __restrict__ dst,
                                 const int* __restrict__ off, unsigned* __restrict__ ebuf,
                                 int E, int NB, int BK) {
    __shared__ int cur[256];
    int t = threadIdx.x;
    if (t < BK) cur[t] = off[t * NB + blockIdx.x];
    __syncthreads();
    int base = blockIdx.x * 8192;
    for (int i = t; i < 8192; i += 256) {
        int e = base + i;
        if (e < E) {
            int d = dst[e];
            int pos = atomicAdd(&cur[d >> 8], 1);
            ebuf[pos] = ((unsigned)src[e] << 8) | (unsigned)(d & 255);
        }
    }
}

__global__ void finalize_kernel(const unsigned* __restrict__ ebuf, const int* __restrict__ off,
                                int* __restrict__ col, int* __restrict__ rowptr,
                                float* __restrict__ dinv, int* __restrict__ deg,
                                int N, int NB, int E) {
    __shared__ int hist[256], scn[256], cur[256];
    int b = blockIdx.x, t = threadIdx.x;
    int base = off[b * NB];
    int end  = off[(b + 1) * NB];
    int M = end - base;
    hist[t] = 0;
    __syncthreads();
    for (int i = t; i < M; i += 256) atomicAdd(&hist[ebuf[base + i] & 255u], 1);
    __syncthreads();
    scn[t] = hist[t];
    for (int o = 1; o < 256; o <<= 1) {
        __syncthreads();
        int u = (t >= o) ? scn[t - o] : 0;
        __syncthreads();
        scn[t] += u;
    }
    __syncthreads();
    int excl = scn[t] - hist[t];
    int node = b * 256 + t;
    if (node < N) {
        rowptr[node] = base + excl;
        dinv[node] = rsqrtf((float)(hist[t] + 1));
        deg[node] = hist[t];            // plain store (no atomics)
    }
    if (b == 0 && t == 0) rowptr[N] = E;
    cur[t] = base + excl;
    __syncthreads();
    for (int i = t; i < M; i += 256) {
        unsigned w = ebuf[base + i];
        int pos = atomicAdd(&cur[w & 255u], 1);
        col[pos] = (int)(w >> 8);
    }
}

// ----------------- degree-sort permutation (block-aggregated) --------------
// dhist: per-block LDS histogram -> <=1 global atomic per bin per block.
__global__ void dhist_kernel(const int* __restrict__ deg, int* __restrict__ dcnt, int N) {
    __shared__ int h[256];
    int t = threadIdx.x;
    h[t] = 0;
    __syncthreads();
    int i = blockIdx.x * 256 + t;
    if (i < N) {
        int d = deg[i];
        if (d > 255) d = 255;
        atomicAdd(&h[d], 1);
    }
    __syncthreads();
    if (h[t]) atomicAdd(&dcnt[t], h[t]);
}

__global__ void perm_scan_kernel(int* __restrict__ dcnt) {
    __shared__ int s[256];
    int t = threadIdx.x;
    int v = dcnt[t];
    s[t] = v;
    for (int o = 1; o < 256; o <<= 1) {
        __syncthreads();
        int u = (t >= o) ? s[t - o] : 0;
        __syncthreads();
        s[t] += u;
    }
    __syncthreads();
    dcnt[t] = s[t] - v;   // exclusive prefix = bucket base (reused as cursor)
}

// scatter: block reserves a per-bin RANGE with one atomic per bin, then
// ranks nodes locally via LDS atomics -> direct writes, no per-node globals.
__global__ void perm_scatter_kernel(const int* __restrict__ deg, int* __restrict__ dcnt,
                                    int* __restrict__ perm, int N) {
    __shared__ int h[256], base[256], cur[256];
    int t = threadIdx.x;
    h[t] = 0;
    __syncthreads();
    int i = blockIdx.x * 256 + t;
    int d = 0;
    if (i < N) {
        d = deg[i];
        if (d > 255) d = 255;
        atomicAdd(&h[d], 1);
    }
    __syncthreads();
    if (h[t]) base[t] = atomicAdd(&dcnt[t], h[t]);
    cur[t] = 0;
    __syncthreads();
    if (i < N) {
        int r = atomicAdd(&cur[d], 1);
        perm[base[d] + r] = i;
    }
}

// -------------------------- weight pre-pack --------------------------------
__global__ void packw_kernel(const float* __restrict__ W1l, const float* __restrict__ W1r,
                             const float* __restrict__ W2l, const float* __restrict__ W2r,
                             const float* __restrict__ Wg,
                             unsigned short* __restrict__ p1h, unsigned short* __restrict__ p1l,
                             unsigned short* __restrict__ p2h, unsigned short* __restrict__ p2l,
                             unsigned short* __restrict__ p3h, unsigned short* __restrict__ p3l) {
    int which = blockIdx.y;
    const float* W;
    unsigned short *hi, *lo;
    int K, Mp, colOff, T;
    if (which == 0)      { W = W1l; hi = p1h; lo = p1l; K = 128; Mp = 128; colOff = 0;   T = 16; }
    else if (which == 1) { W = W1r; hi = p1h; lo = p1l; K = 128; Mp = 128; colOff = 128; T = 16; }
    else if (which == 2) { W = W2l; hi = p2h; lo = p2l; K = 128; Mp = 64;  colOff = 0;   T = 8;  }
    else if (which == 3) { W = W2r; hi = p2h; lo = p2l; K = 128; Mp = 64;  colOff = 64;  T = 8;  }
    else                 { W = Wg;  hi = p3h; lo = p3l; K = 64;  Mp = 64;  colOff = 0;   T = 4;  }
    int idx = blockIdx.x * blockDim.x + threadIdx.x;
    if (idx >= K * Mp) return;
    int k = idx / Mp, m = idx % Mp;
    float w = W[(size_t)k * Mp + m];
    int colI = colOff + m;
    int s = k >> 5, kk = k & 31, qq = kk >> 3, j = kk & 7;
    int tt = colI >> 4, n = colI & 15;
    int lane = qq * 16 + n;
    size_t pos = ((size_t)(s * T + tt) * 64 + lane) * 8 + j;
    unsigned short h = f32_bf16_hi(w);
    hi[pos] = h;
    lo[pos] = f32_bf16_hi(w - bf16_to_f32(h));
}

// --------------------------- gemm1 (K=128, M=256) --------------------------
// A-loads hoisted. y=0 -> p8 (fp8 e4m3, LANE-PACKED: byte pos(f) =
// ((f>>3)&3)*32 + (f>>5)*8 + (f&7)), y=1 -> q16 (fp16).
__launch_bounds__(256)
__global__ void gemm1_kernel(const float* __restrict__ A,
                             const unsigned short* __restrict__ Whi,
                             const unsigned short* __restrict__ Wlo,
                             unsigned char* __restrict__ outA8, __half* __restrict__ outB, int N) {
    constexpr int Ttot = 16, TB = 8;
    __shared__ __align__(16) unsigned char pk[4][16][128];
    const int lane = threadIdx.x & 63;
    const int wave = threadIdx.x >> 6;
    const int m = lane & 15, q = lane >> 4;
    const int t0 = blockIdx.y * TB;
    const int row0 = blockIdx.x * 64 + wave * 16;
    int arow = row0 + m;
    if (arow >= N) arow = N - 1;
    const float* ap = A + (size_t)arow * 128 + q * 8;

    float av[4][8];
#pragma unroll
    for (int s = 0; s < 4; ++s) {
        *(float4*)(av[s])     = *(const float4*)(ap + s * 32);
        *(float4*)(av[s] + 4) = *(const float4*)(ap + s * 32 + 4);
    }
    bf16x8 ahi[4], alo[4];
#pragma unroll
    for (int s = 0; s < 4; ++s)
#pragma unroll
        for (int i = 0; i < 8; ++i) {
            unsigned short h = f32_bf16_hi(av[s][i]);
            ahi[s][i] = (short)h;
            alo[s][i] = (short)f32_bf16_hi(av[s][i] - bf16_to_f32(h));
        }

    f32x4 acc[TB];
#pragma unroll
    for (int t = 0; t < TB; ++t) acc[t] = (f32x4)(0.f);
    const bf16x8* whp = (const bf16x8*)Whi;
    const bf16x8* wlp = (const bf16x8*)Wlo;
#pragma unroll
    for (int s = 0; s < 4; ++s) {
        const int base = (s * Ttot + t0) * 64 + lane;
#pragma unroll
        for (int t = 0; t < TB; ++t) {
            bf16x8 wh = whp[base + t * 64];
            bf16x8 wl = wlp[base + t * 64];
            acc[t] = __builtin_amdgcn_mfma_f32_16x16x32_bf16(ahi[s], wh, acc[t], 0, 0, 0);
            acc[t] = __builtin_amdgcn_mfma_f32_16x16x32_bf16(alo[s], wh, acc[t], 0, 0, 0);
            acc[t] = __builtin_amdgcn_mfma_f32_16x16x32_bf16(ahi[s], wl, acc[t], 0, 0, 0);
        }
    }

    if (blockIdx.y == 0) {
#pragma unroll
        for (int r = 0; r < 4; ++r) {
            int row = q * 4 + r;
            int sw = (row & 3) << 5;
#pragma unroll
            for (int t = 0; t < 8; t += 2) {
                int w = __builtin_amdgcn_cvt_pk_fp8_f32(acc[t][r], acc[t + 1][r], 0, false);
                int off = (t >> 1) * 8 + (m & 7);
                int c0 = ((2 * t + (m >> 3)) & 3) * 32 + off;
                int c1 = ((2 * t + 2 + (m >> 3)) & 3) * 32 + off;
                pk[wave][row][c0 ^ sw] = (unsigned char)(w & 0xff);
                pk[wave][row][c1 ^ sw] = (unsigned char)((w >> 8) & 0xff);
            }
        }
        __syncthreads();
        int rr = lane >> 2, qt = lane & 3;
        int grow = row0 + rr;
        if (grow < N) {
            const unsigned char* srcp = &pk[wave][rr][(qt ^ (rr & 3)) * 32];
            uint4 v0 = *(const uint4*)(srcp);
            uint4 v1 = *(const uint4*)(srcp + 16);
            *(uint4*)(outA8 + (size_t)grow * 128 + qt * 32) = v0;
            *(uint4*)(outA8 + (size_t)grow * 128 + qt * 32 + 16) = v1;
        }
    } else {
#pragma unroll
        for (int r = 0; r < 4; ++r) {
            int row = row0 + q * 4 + r;
            if (row < N) {
#pragma unroll
                for (int t = 0; t < TB; ++t) {
                    int c = (t0 + t) * 16 + m - 128;
                    outB[(size_t)row * 128 + c] = __float2half(acc[t][r]);
                }
            }
        }
    }
}

// ------------------- FUSED: agg1+relu+gemm2 (K=128) ------------------------
// Pair-split, 32 perm-slots/block; nodes from degree-sorted perm[] so each
// 16-node group has ~equal degree (divergence ~0). Lane-packed p8 gather
// (2 x uint4/lane/edge). Wave 0 writes r8 (fp8), wave 1 writes s16.
__launch_bounds__(256)
__global__ void sage2_fused_kernel(const unsigned char* __restrict__ p8, const __half* __restrict__ q16,
                                   const int* __restrict__ rowptr, const int* __restrict__ col,
                                   const int* __restrict__ perm,
                                   const float* __restrict__ b1l,
                                   const unsigned short* __restrict__ Whi,
                                   const unsigned short* __restrict__ Wlo,
                                   unsigned char* __restrict__ r8, __half* __restrict__ s16, int N) {
    __shared__ float part[4][64][16];
    const int lane = threadIdx.x & 63;
    const int wave = threadIdx.x >> 6;
    const int pairH = wave & 1;
    const int grp   = wave >> 1;
    const int m = lane & 15, q = lane >> 4;
    const int row0 = blockIdx.x * 32 + grp * 16;
    int prow = row0 + m;
    int node = perm[(prow < N) ? prow : (N - 1)];
    int sAll = rowptr[node];
    int eAll = (prow < N) ? rowptr[node + 1] : sAll;
    int deg  = eAll - sAll;
    int half0 = (deg + 1) >> 1;
    int sIdx = sAll + (pairH ? half0 : 0);
    int eIdx = pairH ? eAll : (sAll + half0);

    float acc[4][8];
#pragma unroll
    for (int s = 0; s < 4; ++s)
#pragma unroll
        for (int i = 0; i < 8; ++i) acc[s][i] = 0.f;

    const unsigned char* pb = p8 + q * 32;
    int ptr = sIdx;
    for (; ptr + 4 <= eIdx; ptr += 4) {
        int j0 = col[ptr], j1 = col[ptr + 1], j2 = col[ptr + 2], j3 = col[ptr + 3];
        uint4 uA[4], uB[4];
        uA[0] = *(const uint4*)(pb + (size_t)j0 * 128);
        uB[0] = *(const uint4*)(pb + (size_t)j0 * 128 + 16);
        uA[1] = *(const uint4*)(pb + (size_t)j1 * 128);
        uB[1] = *(const uint4*)(pb + (size_t)j1 * 128 + 16);
        uA[2] = *(const uint4*)(pb + (size_t)j2 * 128);
        uB[2] = *(const uint4*)(pb + (size_t)j2 * 128 + 16);
        uA[3] = *(const uint4*)(pb + (size_t)j3 * 128);
        uB[3] = *(const uint4*)(pb + (size_t)j3 * 128 + 16);
#pragma unroll
        for (int e = 0; e < 4; ++e) {
            dec16(uA[e], acc[0], acc[1]);
            dec16(uB[e], acc[2], acc[3]);
        }
    }
    for (; ptr < eIdx; ++ptr) {
        int j0 = col[ptr];
        uint4 uA = *(const uint4*)(pb + (size_t)j0 * 128);
        uint4 uB = *(const uint4*)(pb + (size_t)j0 * 128 + 16);
        dec16(uA, acc[0], acc[1]);
        dec16(uB, acc[2], acc[3]);
    }

    // cross-wave combine: two chunks of 4 float4 slots each, XOR-swizzled
    float* ap = &acc[0][0];
    const int swz = lane & 3;
#pragma unroll
    for (int c = 0; c < 2; ++c) {
        if (c) __syncthreads();
#pragma unroll
        for (int sl = 0; sl < 4; ++sl)
            *(float4*)&part[wave][lane][(sl ^ swz) * 4] =
                *(const float4*)(ap + (c * 4 + sl) * 4);
        __syncthreads();
#pragma unroll
        for (int sl = 0; sl < 4; ++sl) {
            float4 pv = *(const float4*)&part[wave ^ 1][lane][(sl ^ swz) * 4];
            int g = (c * 4 + sl) * 4;
            ap[g]     += pv.x;
            ap[g + 1] += pv.y;
            ap[g + 2] += pv.z;
            ap[g + 3] += pv.w;
        }
    }

    float inv = 1.0f / fmaxf((float)deg, 1.0f);
    bf16x8 ahi[4], alo[4];
#pragma unroll
    for (int s = 0; s < 4; ++s) {
        H8 qv;
        qv.f4 = *(const float4*)(q16 + (size_t)node * 128 + s * 32 + q * 8);
        float bv[8];
        *(float4*)(bv)     = *(const float4*)(b1l + s * 32 + q * 8);
        *(float4*)(bv + 4) = *(const float4*)(b1l + s * 32 + q * 8 + 4);
#pragma unroll
        for (int i = 0; i < 8; ++i) {
            float qf = __half2float(((const __half*)&qv)[i]);
            float h = fmaxf(acc[s][i] * inv + qf + bv[i], 0.f);
            unsigned short hb = f32_bf16_hi(h);
            ahi[s][i] = (short)hb;
            alo[s][i] = (short)f32_bf16_hi(h - bf16_to_f32(hb));
        }
    }

    // MFMA: this wave computes tiles tg = pairH*4 + t (t=0..3)
    f32x4 accm[4];
#pragma unroll
    for (int t = 0; t < 4; ++t) accm[t] = (f32x4)(0.f);
    const bf16x8* whp = (const bf16x8*)Whi;
    const bf16x8* wlp = (const bf16x8*)Wlo;
#pragma unroll
    for (int s = 0; s < 4; ++s) {
        const int base = (s * 8 + pairH * 4) * 64 + lane;
#pragma unroll
        for (int t = 0; t < 4; ++t) {
            bf16x8 wh = whp[base + t * 64];
            bf16x8 wl = wlp[base + t * 64];
            accm[t] = __builtin_amdgcn_mfma_f32_16x16x32_bf16(ahi[s], wh, accm[t], 0, 0, 0);
            accm[t] = __builtin_amdgcn_mfma_f32_16x16x32_bf16(alo[s], wh, accm[t], 0, 0, 0);
            accm[t] = __builtin_amdgcn_mfma_f32_16x16x32_bf16(ahi[s], wl, accm[t], 0, 0, 0);
        }
    }
#pragma unroll
    for (int r = 0; r < 4; ++r) {
        int ridx = row0 + q * 4 + r;
        if (ridx < N) {
            int onode = __shfl(node, q * 4 + r, 64);   // node of output row
            if (pairH == 0) {
                // r8: fp8 bytes at lane-packed pos(c) = ((c>>3)&3)*16 + (c>>5)*8 + (c&7)
#pragma unroll
                for (int t = 0; t < 4; ++t) {
                    int c = t * 16 + m;
                    int pos = ((c >> 3) & 3) * 16 + ((c >> 5) & 1) * 8 + (c & 7);
                    r8[(size_t)onode * 64 + pos] = enc8(accm[t][r]);
                }
            } else {
#pragma unroll
                for (int t = 0; t < 4; ++t) {
                    int c = t * 16 + m;
                    s16[(size_t)onode * 64 + c] = __float2half(accm[t][r]);
                }
            }
        }
    }
}

// --------------- FUSED: agg2+softmax+gemm3 (K=64, dinv scale) --------------
// Pair-split, degree-sorted perm; lane-packed r8 gather (1 uint4/lane/edge).
// Single fp16 tp16 output (N x 64).
__launch_bounds__(256)
__global__ void gcn_prep_fused_kernel(const unsigned char* __restrict__ r8, const __half* __restrict__ s16,
                                      const int* __restrict__ rowptr, const int* __restrict__ col,
                                      const int* __restrict__ perm,
                                      const float* __restrict__ b2l,
                                      const unsigned short* __restrict__ Whi,
                                      const unsigned short* __restrict__ Wlo,
                                      const float* __restrict__ dinv,
                                      __half* __restrict__ tp16, int N) {
    __shared__ float part[4][64][16];
    const int lane = threadIdx.x & 63;
    const int wave = threadIdx.x >> 6;
    const int pairH = wave & 1;
    const int grp   = wave >> 1;
    const int m = lane & 15, q = lane >> 4;
    const int row0 = blockIdx.x * 32 + grp * 16;
    int prow = row0 + m;
    int node = perm[(prow < N) ? prow : (N - 1)];
    int sAll = rowptr[node];
    int eAll = (prow < N) ? rowptr[node + 1] : sAll;
    int deg  = eAll - sAll;
    int half0 = (deg + 1) >> 1;
    int sIdx = sAll + (pairH ? half0 : 0);
    int eIdx = pairH ? eAll : (sAll + half0);

    float acc[2][8];
#pragma unroll
    for (int s = 0; s < 2; ++s)
#pragma unroll
        for (int i = 0; i < 8; ++i) acc[s][i] = 0.f;

    const unsigned char* rb = r8 + q * 16;
    int ptr = sIdx;
    for (; ptr + 4 <= eIdx; ptr += 4) {
        int j0 = col[ptr], j1 = col[ptr + 1], j2 = col[ptr + 2], j3 = col[ptr + 3];
        uint4 u0 = *(const uint4*)(rb + (size_t)j0 * 64);
        uint4 u1 = *(const uint4*)(rb + (size_t)j1 * 64);
        uint4 u2 = *(const uint4*)(rb + (size_t)j2 * 64);
        uint4 u3 = *(const uint4*)(rb + (size_t)j3 * 64);
        dec16(u0, acc[0], acc[1]);
        dec16(u1, acc[0], acc[1]);
        dec16(u2, acc[0], acc[1]);
        dec16(u3, acc[0], acc[1]);
    }
    for (; ptr < eIdx; ++ptr) {
        int j0 = col[ptr];
        uint4 u0 = *(const uint4*)(rb + (size_t)j0 * 64);
        dec16(u0, acc[0], acc[1]);
    }

    // cross-wave combine: single chunk (4 float4 slots), XOR-swizzled
    float* ap = &acc[0][0];
    const int swz = lane & 3;
#pragma unroll
    for (int sl = 0; sl < 4; ++sl)
        *(float4*)&part[wave][lane][(sl ^ swz) * 4] = *(const float4*)(ap + sl * 4);
    __syncthreads();
#pragma unroll
    for (int sl = 0; sl < 4; ++sl) {
        float4 pv = *(const float4*)&part[wave ^ 1][lane][(sl ^ swz) * 4];
        ap[sl * 4]     += pv.x;
        ap[sl * 4 + 1] += pv.y;
        ap[sl * 4 + 2] += pv.z;
        ap[sl * 4 + 3] += pv.w;
    }

    float inv = 1.0f / fmaxf((float)deg, 1.0f);
    float v[2][8];
    float mx = -1e30f;
#pragma unroll
    for (int s = 0; s < 2; ++s) {
        H8 sv;
        sv.f4 = *(const float4*)(s16 + (size_t)node * 64 + s * 32 + q * 8);
        float bv[8];
        *(float4*)(bv)     = *(const float4*)(b2l + s * 32 + q * 8);
        *(float4*)(bv + 4) = *(const float4*)(b2l + s * 32 + q * 8 + 4);
#pragma unroll
        for (int i = 0; i < 8; ++i) {
            float sf = __half2float(((const __half*)&sv)[i]);
            v[s][i] = acc[s][i] * inv + sf + bv[i];
            mx = fmaxf(mx, v[s][i]);
        }
    }
    mx = fmaxf(mx, __shfl_xor(mx, 16, 64));
    mx = fmaxf(mx, __shfl_xor(mx, 32, 64));
    float sm = 0.f;
#pragma unroll
    for (int s = 0; s < 2; ++s)
#pragma unroll
        for (int i = 0; i < 8; ++i) {
            v[s][i] = expf(v[s][i] - mx);
            sm += v[s][i];
        }
    sm += __shfl_xor(sm, 16, 64);
    sm += __shfl_xor(sm, 32, 64);
    float is = 1.0f / sm;

    bf16x8 ahi[2], alo[2];
#pragma unroll
    for (int s = 0; s < 2; ++s)
#pragma unroll
        for (int i = 0; i < 8; ++i) {
            float h = v[s][i] * is;
            unsigned short hb = f32_bf16_hi(h);
            ahi[s][i] = (short)hb;
            alo[s][i] = (short)f32_bf16_hi(h - bf16_to_f32(hb));
        }

    // MFMA: this wave computes tiles tg = pairH*2 + t (t=0..1)
    f32x4 accm[2];
#pragma unroll
    for (int t = 0; t < 2; ++t) accm[t] = (f32x4)(0.f);
    const bf16x8* whp = (const bf16x8*)Whi;
    const bf16x8* wlp = (const bf16x8*)Wlo;
#pragma unroll
    for (int s = 0; s < 2; ++s) {
        const int base = (s * 4 + pairH * 2) * 64 + lane;
#pragma unroll
        for (int t = 0; t < 2; ++t) {
            bf16x8 wh = whp[base + t * 64];
            bf16x8 wl = wlp[base + t * 64];
            accm[t] = __builtin_amdgcn_mfma_f32_16x16x32_bf16(ahi[s], wh, accm[t], 0, 0, 0);
            accm[t] = __builtin_amdgcn_mfma_f32_16x16x32_bf16(alo[s], wh, accm[t], 0, 0, 0);
            accm[t] = __builtin_amdgcn_mfma_f32_16x16x32_bf16(ahi[s], wl, accm[t], 0, 0, 0);
        }
    }
#pragma unroll
    for (int r = 0; r < 4; ++r) {
        int ridx = row0 + q * 4 + r;
        if (ridx < N) {
            int onode = __shfl(node, q * 4 + r, 64);
            float sc = dinv[onode];
#pragma unroll
            for (int t = 0; t < 2; ++t) {
                int c = (pairH * 2 + t) * 16 + m;
                tp16[(size_t)onode * 64 + c] = __float2half(accm[t][r] * sc);
            }
        }
    }
}

// ------------------------------ gcn gather ---------------------------------
// half2 lanes: 32 feature-pair lanes x 2 edge-parity groups; combine via
// shfl_xor(32). One wave per node -> no inter-node divergence (no perm).
__global__ void gcn_agg_kernel(const __half* __restrict__ tp,
                               const int* __restrict__ rowptr, const int* __restrict__ col,
                               const float* __restrict__ dinv, const float* __restrict__ bg,
                               float* __restrict__ out, int N) {
    int node = blockIdx.x * 4 + (threadIdx.x >> 6);
    if (node >= N) return;
    int lane = threadIdx.x & 63;
    int f2 = lane & 31;   // features 2*f2, 2*f2+1
    int ep = lane >> 5;   // edge parity
    int s = rowptr[node], e = rowptr[node + 1];
    float ax[8], ay[8];
#pragma unroll
    for (int k = 0; k < 8; ++k) { ax[k] = 0.f; ay[k] = 0.f; }
    int p = s;
    for (; p + 16 <= e; p += 16) {
#pragma unroll
        for (int k = 0; k < 8; ++k) {
            int j = col[p + 2 * k + ep];
            float2 f = __half22float2(*(const __half2*)(tp + (size_t)j * 64 + 2 * f2));
            ax[k] += f.x;
            ay[k] += f.y;
        }
    }
    for (int t = p + ep; t < e; t += 2) {
        int j = col[t];
        float2 f = __half22float2(*(const __half2*)(tp + (size_t)j * 64 + 2 * f2));
        ax[0] += f.x;
        ay[0] += f.y;
    }
    float sx = ((ax[0] + ax[1]) + (ax[2] + ax[3])) + ((ax[4] + ax[5]) + (ax[6] + ax[7]));
    float sy = ((ay[0] + ay[1]) + (ay[2] + ay[3])) + ((ay[4] + ay[5]) + (ay[6] + ay[7]));
    sx += __shfl_xor(sx, 32, 64);
    sy += __shfl_xor(sy, 32, 64);
    if (ep == 0) {
        float2 selfv = __half22float2(*(const __half2*)(tp + (size_t)node * 64 + 2 * f2));
        float di = dinv[node];
        float2 o;
        o.x = (sx + selfv.x) * di + bg[2 * f2];
        o.y = (sy + selfv.y) * di + bg[2 * f2 + 1];
        *(float2*)(out + (size_t)node * 64 + 2 * f2) = o;
    }
}

extern "C" void kernel_launch(void* const* d_in, const int* in_sizes, int n_in,
                              void* d_out, int out_size, void* d_ws, size_t ws_size,
                              hipStream_t stream) {
    const float* x = (const float*)d_in[0];
    const int* ei = (const int*)d_in[1];    // int32 per harness conversion
    const float* W1l = (const float*)d_in[2];
    const float* b1l = (const float*)d_in[3];
    const float* W1r = (const float*)d_in[4];
    const float* W2l = (const float*)d_in[5];
    const float* b2l = (const float*)d_in[6];
    const float* W2r = (const float*)d_in[7];
    const float* Wg  = (const float*)d_in[8];
    const float* bg  = (const float*)d_in[9];

    const int N = in_sizes[0] / 128;
    const int E = in_sizes[1] / 2;
    const int* srcp = ei;
    const int* dstp = ei + E;

    const int NB = (E + 8191) / 8192;
    const int BK = (N + 255) >> 8;
    const int len = BK * NB;

    // workspace layout
    float* ws = (float*)d_ws;
    float* dinv = ws;                              // N
    unsigned char* p8 = (unsigned char*)(dinv + N);   // N*128 B (fp8)
    __half* q16 = (__half*)(p8 + (size_t)N * 128);    // N*128 half
    unsigned char* r8 = (unsigned char*)(q16 + (size_t)N * 128); // N*64 B (fp8)
    __half* s16 = (__half*)(r8 + (size_t)N * 64);     // N*64 half
    __half* tp16 = s16 + (size_t)N * 64;              // N*64 half
    int* rowptr = (int*)(tp16 + (size_t)N * 64);   // N+1
    int* off    = rowptr + (N + 1);                // len+2
    int* colbuf = off + len + 2;                   // E
    unsigned* ebuf = (unsigned*)(colbuf + E);      // E
    int* bsum   = (int*)(ebuf + E);                // 32
    int* deg    = bsum + 32;                       // N
    int* dcnt   = deg + N;                         // 256
    int* perm   = dcnt + 256;                      // N
    uintptr_t up = (uintptr_t)(perm + N);
    up = (up + 15) & ~(uintptr_t)15;
    unsigned short* p1h = (unsigned short*)up;     // 32768 (128x256)
    unsigned short* p1l = p1h + 32768;
    unsigned short* p2h = p1l + 32768;             // 16384 (128x128)
    unsigned short* p2l = p2h + 16384;
    unsigned short* p3h = p2l + 16384;             // 4096 (64x64)
    unsigned short* p3l = p3h + 4096;

    float* out = (float*)d_out;

    // --- CSR build (radix by dst) ---
    count_kernel<<<NB, 256, 0, stream>>>(dstp, off, dcnt, E, NB, BK);
    const int sn = len + 1;
    const int SBs = (sn + 2047) / 2048;
    scan_reduce_kernel<<<SBs, 256, 0, stream>>>(off, bsum, sn);
    scan_offsets_kernel<<<1, 64, 0, stream>>>(bsum, SBs);
    scan_final_kernel<<<SBs, 256, 0, stream>>>(off, bsum, sn);
    partition_kernel<<<NB, 256, 0, stream>>>(srcp, dstp, off, ebuf, E, NB, BK);
    finalize_kernel<<<BK, 256, 0, stream>>>(ebuf, off, colbuf, rowptr, dinv,
                                            deg, N, NB, E);

    // --- degree-sort permutation (block-aggregated atomics) ---
    const int nb256 = (N + 255) / 256;
    dhist_kernel<<<nb256, 256, 0, stream>>>(deg, dcnt, N);
    perm_scan_kernel<<<1, 256, 0, stream>>>(dcnt);
    perm_scatter_kernel<<<nb256, 256, 0, stream>>>(deg, dcnt, perm, N);

    packw_kernel<<<dim3(64, 5), 256, 0, stream>>>(W1l, W1r, W2l, W2r, Wg,
                                                  p1h, p1l, p2h, p2l, p3h, p3l);

    const int gb  = (N + 63) / 64;   // gemm1
    const int gbf = (N + 31) / 32;   // fused (pair-split)
    const int ab  = (N + 3) / 4;     // gcn_agg

    // gemm1: y=0 -> p8 (fp8, lane-packed), y=1 -> q16 (fp16)
    gemm1_kernel<<<dim3(gb, 2), 256, 0, stream>>>(x, p1h, p1l, p8, q16, N);

    // fused: h1 = relu(mean(p8)+q16+b1l); [r8|s16] = h1 @ [W2l|W2r]
    sage2_fused_kernel<<<gbf, 256, 0, stream>>>(p8, q16, rowptr, colbuf, perm, b1l,
                                                p2h, p2l, r8, s16, N);

    // fused: h2 = softmax(mean(r8)+s16+b2l); tp16 = (h2 @ Wg) * dinv
    gcn_prep_fused_kernel<<<gbf, 256, 0, stream>>>(r8, s16, rowptr, colbuf, perm, b2l,
                                                   p3h, p3l, dinv, tp16, N);

    gcn_agg_kernel<<<ab, 256, 0, stream>>>(tp16, rowptr, colbuf, dinv, bg, out, N);
}

// Round 10
// 256.597 us; speedup vs baseline: 2.1774x; 1.0659x over previous
//
#include <hip/hip_runtime.h>
#include <hip/hip_fp16.h>
#include <math.h>

// ---------------------------------------------------------------------------
// ADSAGE: 2x SAGEConv (mean aggr) + softmax + GCNConv, fp32.
// Aggregate-after-GEMM (mean is linear). GEMMs on matrix cores via
// split-bf16 (3-term). CSR via 2-pass radix sort by dst.
// THIS REV (consolidation, resubmitted after infra failure): degree-sort
// perm REMOVED (R8 A/B: null, and +10MB FETCH from scattered gather
// locality). Dispatch count 14 -> 9: packw merged into count (block-split
// grid); scan_offsets folded into scan_final (each block redundantly scans
// the ~10-entry bsum). Fused kernels are the R5 best-known form
// (pair-split, lane-packed fp8 gathers, 4-edge unroll).
// Gather-wall status: concurrency x2/x4 null, bytes sub-linear, L2
// residency null, ILP null, divergence null -> consistent with per-CU
// MSHR x miss-latency floor. sage2 ~47us is within ~20% of that floor;
// p-fp4 (only remaining 2x) is precision-dead (R4 scaling).
// Pipeline:
//   p8,q16 = x @ [W1l|W1r]                        gemm1
//   r8,s16 = relu(mean(p8)+q16+b1l) @ [W2l|W2r]   FUSED pair-split
//   tp16 = softmax(mean(r8)+s16+b2l) @ Wg * dinv  FUSED pair-split
//   out  = dinv*(sum_j tp[j] + tp[i]) + bg        gather (half2 lanes)
// ---------------------------------------------------------------------------

typedef __attribute__((ext_vector_type(8))) short bf16x8;
typedef __attribute__((ext_vector_type(4))) float f32x4;
typedef __attribute__((ext_vector_type(2))) float f32v2;

__device__ inline unsigned short f32_bf16_hi(float f) {
    unsigned int u = __builtin_bit_cast(unsigned int, f);
    u = (u + 0x7FFFu + ((u >> 16) & 1u)) >> 16;
    return (unsigned short)u;
}
__device__ inline float bf16_to_f32(unsigned short h) {
    unsigned int u = ((unsigned int)h) << 16;
    return __builtin_bit_cast(float, u);
}

union H8 { float4 f4; __half2 h[4]; };

// decode 16 fp8 bytes (one uint4) into two 8-float accumulator slices
__device__ inline void dec16(uint4 u, float* a0, float* a1) {
    f32v2 x0 = __builtin_amdgcn_cvt_pk_f32_fp8(u.x, false);
    f32v2 x1 = __builtin_amdgcn_cvt_pk_f32_fp8(u.x, true);
    f32v2 y0 = __builtin_amdgcn_cvt_pk_f32_fp8(u.y, false);
    f32v2 y1 = __builtin_amdgcn_cvt_pk_f32_fp8(u.y, true);
    a0[0] += x0[0]; a0[1] += x0[1]; a0[2] += x1[0]; a0[3] += x1[1];
    a0[4] += y0[0]; a0[5] += y0[1]; a0[6] += y1[0]; a0[7] += y1[1];
    f32v2 z0 = __builtin_amdgcn_cvt_pk_f32_fp8(u.z, false);
    f32v2 z1 = __builtin_amdgcn_cvt_pk_f32_fp8(u.z, true);
    f32v2 w0 = __builtin_amdgcn_cvt_pk_f32_fp8(u.w, false);
    f32v2 w1 = __builtin_amdgcn_cvt_pk_f32_fp8(u.w, true);
    a1[0] += z0[0]; a1[1] += z0[1]; a1[2] += z1[0]; a1[3] += z1[1];
    a1[4] += w0[0]; a1[5] += w0[1]; a1[6] += w1[0]; a1[7] += w1[1];
}

__device__ inline unsigned char enc8(float v) {
    int w = __builtin_amdgcn_cvt_pk_fp8_f32(v, v, 0, false);
    return (unsigned char)(w & 0xff);
}

// -------------- CSR count (radix by dst) + weight pre-pack -----------------
// blocks [0, NB): per-block dst-range histogram for the radix partition.
// blocks [NB, NB+320): pack the 5 weight matrices into MFMA B-fragment
// layout, split-bf16 (hi+lo). Independent work, one dispatch.
__global__ void count_packw_kernel(const int* __restrict__ dst, int* __restrict__ off,
                                   int E, int NB, int BK,
                                   const float* __restrict__ W1l, const float* __restrict__ W1r,
                                   const float* __restrict__ W2l, const float* __restrict__ W2r,
                                   const float* __restrict__ Wg,
                                   unsigned short* __restrict__ p1h, unsigned short* __restrict__ p1l,
                                   unsigned short* __restrict__ p2h, unsigned short* __restrict__ p2l,
                                   unsigned short* __restrict__ p3h, unsigned short* __restrict__ p3l) {
    __shared__ int hist[256];
    int t = threadIdx.x;
    if ((int)blockIdx.x < NB) {
        hist[t] = 0;
        __syncthreads();
        int base = blockIdx.x * 8192;
        for (int i = t; i < 8192; i += 256) {
            int e = base + i;
            if (e < E) atomicAdd(&hist[dst[e] >> 8], 1);
        }
        __syncthreads();
        if (t < BK) off[1 + t * NB + blockIdx.x] = hist[t];
        if (blockIdx.x == 0 && t == 0) off[0] = 0;
        return;
    }
    int pb = blockIdx.x - NB;
    int which = pb >> 6;
    const float* W;
    unsigned short *hi, *lo;
    int K, Mp, colOff, T;
    if (which == 0)      { W = W1l; hi = p1h; lo = p1l; K = 128; Mp = 128; colOff = 0;   T = 16; }
    else if (which == 1) { W = W1r; hi = p1h; lo = p1l; K = 128; Mp = 128; colOff = 128; T = 16; }
    else if (which == 2) { W = W2l; hi = p2h; lo = p2l; K = 128; Mp = 64;  colOff = 0;   T = 8;  }
    else if (which == 3) { W = W2r; hi = p2h; lo = p2l; K = 128; Mp = 64;  colOff = 64;  T = 8;  }
    else                 { W = Wg;  hi = p3h; lo = p3l; K = 64;  Mp = 64;  colOff = 0;   T = 4;  }
    int idx = (pb & 63) * 256 + t;
    if (idx >= K * Mp) return;
    int k = idx / Mp, m = idx % Mp;
    float w = W[(size_t)k * Mp + m];
    int colI = colOff + m;
    int s = k >> 5, kk = k & 31, qq = kk >> 3, j = kk & 7;
    int tt = colI >> 4, n = colI & 15;
    int lane = qq * 16 + n;
    size_t pos = ((size_t)(s * T + tt) * 64 + lane) * 8 + j;
    unsigned short h = f32_bf16_hi(w);
    hi[pos] = h;
    lo[pos] = f32_bf16_hi(w - bf16_to_f32(h));
}

__global__ void scan_reduce_kernel(const int* __restrict__ data, int* __restrict__ bsum, int n) {
    __shared__ int red[256];
    int t = threadIdx.x;
    int base = blockIdx.x * 2048 + t * 8;
    int s = 0;
    if (base + 8 <= n) {
        int4 a = *(const int4*)(data + base);
        int4 b = *(const int4*)(data + base + 4);
        s = a.x + a.y + a.z + a.w + b.x + b.y + b.z + b.w;
    } else {
        for (int i = 0; i < 8; ++i)
            if (base + i < n) s += data[base + i];
    }
    red[t] = s;
    __syncthreads();
    for (int off = 128; off > 0; off >>= 1) {
        if (t < off) red[t] += red[t + off];
        __syncthreads();
    }
    if (t == 0) bsum[blockIdx.x] = red[0];
}

// scan_final with INLINE block-offset scan (bsum is ~10 entries; each block
// redundantly prefix-sums it -> scan_offsets launch eliminated).
__global__ void scan_final_kernel(int* __restrict__ data, const int* __restrict__ bsum, int n) {
    __shared__ int tsum[256];
    int t = threadIdx.x;
    int bbase = 0;
    for (int i = 0; i < (int)blockIdx.x; ++i) bbase += bsum[i];
    int base = blockIdx.x * 2048 + t * 8;
    int v[8];
    int s = 0;
#pragma unroll
    for (int i = 0; i < 8; ++i) {
        v[i] = (base + i < n) ? data[base + i] : 0;
        s += v[i];
    }
    tsum[t] = s;
    for (int off = 1; off < 256; off <<= 1) {
        __syncthreads();
        int u = (t >= off) ? tsum[t - off] : 0;
        __syncthreads();
        tsum[t] += u;
    }
    __syncthreads();
    int run = bbase + tsum[t] - s;
#pragma unroll
    for (int i = 0; i < 8; ++i) {
        run += v[i];
        if (base + i < n) data[base + i] = run;
    }
}

__global__ void partition_kernel(const int* __restrict__ src, const int* __restrict__ dst,
                                 const int* __restrict__ off, unsigned* __restrict__ ebuf,
                                 int E, int NB, int BK) {
    __shared__ int cur[256];
    int t = threadIdx.x;
    if (t < BK) cur[t] = off[t * NB + blockIdx.x];
    __syncthreads();
    int base = blockIdx.x * 8192;
    for (int i = t; i < 8192; i += 256) {
        int e = base + i;
        if (e < E) {
            int d = dst[e];
            int pos = atomicAdd(&cur[d >> 8], 1);
            ebuf[pos] = ((unsigned)src[e] << 8) | (unsigned)(d & 255);
        }
    }
}

__global__ void finalize_kernel(const unsigned* __restrict__ ebuf, const int* __restrict__ off,
                                int* __restrict__ col, int* __restrict__ rowptr,
                                float* __restrict__ dinv, int N, int NB, int E) {
    __shared__ int hist[256], scn[256], cur[256];
    int b = blockIdx.x, t = threadIdx.x;
    int base = off[b * NB];
    int end  = off[(b + 1) * NB];
    int M = end - base;
    hist[t] = 0;
    __syncthreads();
    for (int i = t; i < M; i += 256) atomicAdd(&hist[ebuf[base + i] & 255u], 1);
    __syncthreads();
    scn[t] = hist[t];
    for (int o = 1; o < 256; o <<= 1) {
        __syncthreads();
        int u = (t >= o) ? scn[t - o] : 0;
        __syncthreads();
        scn[t] += u;
    }
    __syncthreads();
    int excl = scn[t] - hist[t];
    int node = b * 256 + t;
    if (node < N) {
        rowptr[node] = base + excl;
        dinv[node] = rsqrtf((float)(hist[t] + 1));
    }
    if (b == 0 && t == 0) rowptr[N] = E;
    cur[t] = base + excl;
    __syncthreads();
    for (int i = t; i < M; i += 256) {
        unsigned w = ebuf[base + i];
        int pos = atomicAdd(&cur[w & 255u], 1);
        col[pos] = (int)(w >> 8);
    }
}

// --------------------------- gemm1 (K=128, M=256) --------------------------
// A-loads hoisted. y=0 -> p8 (fp8 e4m3, LANE-PACKED: byte pos(f) =
// ((f>>3)&3)*32 + (f>>5)*8 + (f&7)), y=1 -> q16 (fp16).
__launch_bounds__(256)
__global__ void gemm1_kernel(const float* __restrict__ A,
                             const unsigned short* __restrict__ Whi,
                             const unsigned short* __restrict__ Wlo,
                             unsigned char* __restrict__ outA8, __half* __restrict__ outB, int N) {
    constexpr int Ttot = 16, TB = 8;
    __shared__ __align__(16) unsigned char pk[4][16][128];
    const int lane = threadIdx.x & 63;
    const int wave = threadIdx.x >> 6;
    const int m = lane & 15, q = lane >> 4;
    const int t0 = blockIdx.y * TB;
    const int row0 = blockIdx.x * 64 + wave * 16;
    int arow = row0 + m;
    if (arow >= N) arow = N - 1;
    const float* ap = A + (size_t)arow * 128 + q * 8;

    float av[4][8];
#pragma unroll
    for (int s = 0; s < 4; ++s) {
        *(float4*)(av[s])     = *(const float4*)(ap + s * 32);
        *(float4*)(av[s] + 4) = *(const float4*)(ap + s * 32 + 4);
    }
    bf16x8 ahi[4], alo[4];
#pragma unroll
    for (int s = 0; s < 4; ++s)
#pragma unroll
        for (int i = 0; i < 8; ++i) {
            unsigned short h = f32_bf16_hi(av[s][i]);
            ahi[s][i] = (short)h;
            alo[s][i] = (short)f32_bf16_hi(av[s][i] - bf16_to_f32(h));
        }

    f32x4 acc[TB];
#pragma unroll
    for (int t = 0; t < TB; ++t) acc[t] = (f32x4)(0.f);
    const bf16x8* whp = (const bf16x8*)Whi;
    const bf16x8* wlp = (const bf16x8*)Wlo;
#pragma unroll
    for (int s = 0; s < 4; ++s) {
        const int base = (s * Ttot + t0) * 64 + lane;
#pragma unroll
        for (int t = 0; t < TB; ++t) {
            bf16x8 wh = whp[base + t * 64];
            bf16x8 wl = wlp[base + t * 64];
            acc[t] = __builtin_amdgcn_mfma_f32_16x16x32_bf16(ahi[s], wh, acc[t], 0, 0, 0);
            acc[t] = __builtin_amdgcn_mfma_f32_16x16x32_bf16(alo[s], wh, acc[t], 0, 0, 0);
            acc[t] = __builtin_amdgcn_mfma_f32_16x16x32_bf16(ahi[s], wl, acc[t], 0, 0, 0);
        }
    }

    if (blockIdx.y == 0) {
#pragma unroll
        for (int r = 0; r < 4; ++r) {
            int row = q * 4 + r;
            int sw = (row & 3) << 5;
#pragma unroll
            for (int t = 0; t < 8; t += 2) {
                int w = __builtin_amdgcn_cvt_pk_fp8_f32(acc[t][r], acc[t + 1][r], 0, false);
                int off = (t >> 1) * 8 + (m & 7);
                int c0 = ((2 * t + (m >> 3)) & 3) * 32 + off;
                int c1 = ((2 * t + 2 + (m >> 3)) & 3) * 32 + off;
                pk[wave][row][c0 ^ sw] = (unsigned char)(w & 0xff);
                pk[wave][row][c1 ^ sw] = (unsigned char)((w >> 8) & 0xff);
            }
        }
        __syncthreads();
        int rr = lane >> 2, qt = lane & 3;
        int grow = row0 + rr;
        if (grow < N) {
            const unsigned char* srcp = &pk[wave][rr][(qt ^ (rr & 3)) * 32];
            uint4 v0 = *(const uint4*)(srcp);
            uint4 v1 = *(const uint4*)(srcp + 16);
            *(uint4*)(outA8 + (size_t)grow * 128 + qt * 32) = v0;
            *(uint4*)(outA8 + (size_t)grow * 128 + qt * 32 + 16) = v1;
        }
    } else {
#pragma unroll
        for (int r = 0; r < 4; ++r) {
            int row = row0 + q * 4 + r;
            if (row < N) {
#pragma unroll
                for (int t = 0; t < TB; ++t) {
                    int c = (t0 + t) * 16 + m - 128;
                    outB[(size_t)row * 128 + c] = __float2half(acc[t][r]);
                }
            }
        }
    }
}

// ------------------- FUSED: agg1+relu+gemm2 (K=128) ------------------------
// Pair-split, 32 nodes/block; lane-packed p8 gather (2 x uint4/lane/edge).
// Wave 0 writes r8 (fp8 lane-packed), wave 1 writes s16 (fp16).
__launch_bounds__(256)
__global__ void sage2_fused_kernel(const unsigned char* __restrict__ p8, const __half* __restrict__ q16,
                                   const int* __restrict__ rowptr, const int* __restrict__ col,
                                   const float* __restrict__ b1l,
                                   const unsigned short* __restrict__ Whi,
                                   const unsigned short* __restrict__ Wlo,
                                   unsigned char* __restrict__ r8, __half* __restrict__ s16, int N) {
    __shared__ float part[4][64][16];
    const int lane = threadIdx.x & 63;
    const int wave = threadIdx.x >> 6;
    const int pairH = wave & 1;
    const int grp   = wave >> 1;
    const int m = lane & 15, q = lane >> 4;
    const int row0 = blockIdx.x * 32 + grp * 16;
    int node = row0 + m;
    int nclamp = (node < N) ? node : (N - 1);
    int sAll = rowptr[nclamp];
    int eAll = (node < N) ? rowptr[nclamp + 1] : sAll;
    int deg  = eAll - sAll;
    int half0 = (deg + 1) >> 1;
    int sIdx = sAll + (pairH ? half0 : 0);
    int eIdx = pairH ? eAll : (sAll + half0);

    float acc[4][8];
#pragma unroll
    for (int s = 0; s < 4; ++s)
#pragma unroll
        for (int i = 0; i < 8; ++i) acc[s][i] = 0.f;

    const unsigned char* pb = p8 + q * 32;
    int ptr = sIdx;
    for (; ptr + 4 <= eIdx; ptr += 4) {
        int j0 = col[ptr], j1 = col[ptr + 1], j2 = col[ptr + 2], j3 = col[ptr + 3];
        uint4 uA[4], uB[4];
        uA[0] = *(const uint4*)(pb + (size_t)j0 * 128);
        uB[0] = *(const uint4*)(pb + (size_t)j0 * 128 + 16);
        uA[1] = *(const uint4*)(pb + (size_t)j1 * 128);
        uB[1] = *(const uint4*)(pb + (size_t)j1 * 128 + 16);
        uA[2] = *(const uint4*)(pb + (size_t)j2 * 128);
        uB[2] = *(const uint4*)(pb + (size_t)j2 * 128 + 16);
        uA[3] = *(const uint4*)(pb + (size_t)j3 * 128);
        uB[3] = *(const uint4*)(pb + (size_t)j3 * 128 + 16);
#pragma unroll
        for (int e = 0; e < 4; ++e) {
            dec16(uA[e], acc[0], acc[1]);
            dec16(uB[e], acc[2], acc[3]);
        }
    }
    for (; ptr < eIdx; ++ptr) {
        int j0 = col[ptr];
        uint4 uA = *(const uint4*)(pb + (size_t)j0 * 128);
        uint4 uB = *(const uint4*)(pb + (size_t)j0 * 128 + 16);
        dec16(uA, acc[0], acc[1]);
        dec16(uB, acc[2], acc[3]);
    }

    // cross-wave combine: two chunks of 4 float4 slots each, XOR-swizzled
    float* ap = &acc[0][0];
    const int swz = lane & 3;
#pragma unroll
    for (int c = 0; c < 2; ++c) {
        if (c) __syncthreads();
#pragma unroll
        for (int sl = 0; sl < 4; ++sl)
            *(float4*)&part[wave][lane][(sl ^ swz) * 4] =
                *(const float4*)(ap + (c * 4 + sl) * 4);
        __syncthreads();
#pragma unroll
        for (int sl = 0; sl < 4; ++sl) {
            float4 pv = *(const float4*)&part[wave ^ 1][lane][(sl ^ swz) * 4];
            int g = (c * 4 + sl) * 4;
            ap[g]     += pv.x;
            ap[g + 1] += pv.y;
            ap[g + 2] += pv.z;
            ap[g + 3] += pv.w;
        }
    }

    float inv = 1.0f / fmaxf((float)deg, 1.0f);
    bf16x8 ahi[4], alo[4];
#pragma unroll
    for (int s = 0; s < 4; ++s) {
        H8 qv;
        qv.f4 = *(const float4*)(q16 + (size_t)nclamp * 128 + s * 32 + q * 8);
        float bv[8];
        *(float4*)(bv)     = *(const float4*)(b1l + s * 32 + q * 8);
        *(float4*)(bv + 4) = *(const float4*)(b1l + s * 32 + q * 8 + 4);
#pragma unroll
        for (int i = 0; i < 8; ++i) {
            float qf = __half2float(((const __half*)&qv)[i]);
            float h = fmaxf(acc[s][i] * inv + qf + bv[i], 0.f);
            unsigned short hb = f32_bf16_hi(h);
            ahi[s][i] = (short)hb;
            alo[s][i] = (short)f32_bf16_hi(h - bf16_to_f32(hb));
        }
    }

    // MFMA: this wave computes tiles tg = pairH*4 + t (t=0..3)
    f32x4 accm[4];
#pragma unroll
    for (int t = 0; t < 4; ++t) accm[t] = (f32x4)(0.f);
    const bf16x8* whp = (const bf16x8*)Whi;
    const bf16x8* wlp = (const bf16x8*)Wlo;
#pragma unroll
    for (int s = 0; s < 4; ++s) {
        const int base = (s * 8 + pairH * 4) * 64 + lane;
#pragma unroll
        for (int t = 0; t < 4; ++t) {
            bf16x8 wh = whp[base + t * 64];
            bf16x8 wl = wlp[base + t * 64];
            accm[t] = __builtin_amdgcn_mfma_f32_16x16x32_bf16(ahi[s], wh, accm[t], 0, 0, 0);
            accm[t] = __builtin_amdgcn_mfma_f32_16x16x32_bf16(alo[s], wh, accm[t], 0, 0, 0);
            accm[t] = __builtin_amdgcn_mfma_f32_16x16x32_bf16(ahi[s], wl, accm[t], 0, 0, 0);
        }
    }
#pragma unroll
    for (int r = 0; r < 4; ++r) {
        int row = row0 + q * 4 + r;
        if (row < N) {
            if (pairH == 0) {
                // r8: fp8 bytes at lane-packed pos(c) = ((c>>3)&3)*16 + (c>>5)*8 + (c&7)
#pragma unroll
                for (int t = 0; t < 4; ++t) {
                    int c = t * 16 + m;
                    int pos = ((c >> 3) & 3) * 16 + ((c >> 5) & 1) * 8 + (c & 7);
                    r8[(size_t)row * 64 + pos] = enc8(accm[t][r]);
                }
            } else {
#pragma unroll
                for (int t = 0; t < 4; ++t) {
                    int c = t * 16 + m;
                    s16[(size_t)row * 64 + c] = __float2half(accm[t][r]);
                }
            }
        }
    }
}

// --------------- FUSED: agg2+softmax+gemm3 (K=64, dinv scale) --------------
// Pair-split; lane-packed r8 gather (1 uint4/lane/edge). Single fp16 tp16
// output (N x 64).
__launch_bounds__(256)
__global__ void gcn_prep_fused_kernel(const unsigned char* __restrict__ r8, const __half* __restrict__ s16,
                                      const int* __restrict__ rowptr, const int* __restrict__ col,
                                      const float* __restrict__ b2l,
                                      const unsigned short* __restrict__ Whi,
                                      const unsigned short* __restrict__ Wlo,
                                      const float* __restrict__ dinv,
                                      __half* __restrict__ tp16, int N) {
    __shared__ float part[4][64][16];
    const int lane = threadIdx.x & 63;
    const int wave = threadIdx.x >> 6;
    const int pairH = wave & 1;
    const int grp   = wave >> 1;
    const int m = lane & 15, q = lane >> 4;
    const int row0 = blockIdx.x * 32 + grp * 16;
    int node = row0 + m;
    int nclamp = (node < N) ? node : (N - 1);
    int sAll = rowptr[nclamp];
    int eAll = (node < N) ? rowptr[nclamp + 1] : sAll;
    int deg  = eAll - sAll;
    int half0 = (deg + 1) >> 1;
    int sIdx = sAll + (pairH ? half0 : 0);
    int eIdx = pairH ? eAll : (sAll + half0);

    float acc[2][8];
#pragma unroll
    for (int s = 0; s < 2; ++s)
#pragma unroll
        for (int i = 0; i < 8; ++i) acc[s][i] = 0.f;

    const unsigned char* rb = r8 + q * 16;
    int ptr = sIdx;
    for (; ptr + 4 <= eIdx; ptr += 4) {
        int j0 = col[ptr], j1 = col[ptr + 1], j2 = col[ptr + 2], j3 = col[ptr + 3];
        uint4 u0 = *(const uint4*)(rb + (size_t)j0 * 64);
        uint4 u1 = *(const uint4*)(rb + (size_t)j1 * 64);
        uint4 u2 = *(const uint4*)(rb + (size_t)j2 * 64);
        uint4 u3 = *(const uint4*)(rb + (size_t)j3 * 64);
        dec16(u0, acc[0], acc[1]);
        dec16(u1, acc[0], acc[1]);
        dec16(u2, acc[0], acc[1]);
        dec16(u3, acc[0], acc[1]);
    }
    for (; ptr < eIdx; ++ptr) {
        int j0 = col[ptr];
        uint4 u0 = *(const uint4*)(rb + (size_t)j0 * 64);
        dec16(u0, acc[0], acc[1]);
    }

    // cross-wave combine: single chunk (4 float4 slots), XOR-swizzled
    float* ap = &acc[0][0];
    const int swz = lane & 3;
#pragma unroll
    for (int sl = 0; sl < 4; ++sl)
        *(float4*)&part[wave][lane][(sl ^ swz) * 4] = *(const float4*)(ap + sl * 4);
    __syncthreads();
#pragma unroll
    for (int sl = 0; sl < 4; ++sl) {
        float4 pv = *(const float4*)&part[wave ^ 1][lane][(sl ^ swz) * 4];
        ap[sl * 4]     += pv.x;
        ap[sl * 4 + 1] += pv.y;
        ap[sl * 4 + 2] += pv.z;
        ap[sl * 4 + 3] += pv.w;
    }

    float inv = 1.0f / fmaxf((float)deg, 1.0f);
    float v[2][8];
    float mx = -1e30f;
#pragma unroll
    for (int s = 0; s < 2; ++s) {
        H8 sv;
        sv.f4 = *(const float4*)(s16 + (size_t)nclamp * 64 + s * 32 + q * 8);
        float bv[8];
        *(float4*)(bv)     = *(const float4*)(b2l + s * 32 + q * 8);
        *(float4*)(bv + 4) = *(const float4*)(b2l + s * 32 + q * 8 + 4);
#pragma unroll
        for (int i = 0; i < 8; ++i) {
            float sf = __half2float(((const __half*)&sv)[i]);
            v[s][i] = acc[s][i] * inv + sf + bv[i];
            mx = fmaxf(mx, v[s][i]);
        }
    }
    mx = fmaxf(mx, __shfl_xor(mx, 16, 64));
    mx = fmaxf(mx, __shfl_xor(mx, 32, 64));
    float sm = 0.f;
#pragma unroll
    for (int s = 0; s < 2; ++s)
#pragma unroll
        for (int i = 0; i < 8; ++i) {
            v[s][i] = expf(v[s][i] - mx);
            sm += v[s][i];
        }
    sm += __shfl_xor(sm, 16, 64);
    sm += __shfl_xor(sm, 32, 64);
    float is = 1.0f / sm;

    bf16x8 ahi[2], alo[2];
#pragma unroll
    for (int s = 0; s < 2; ++s)
#pragma unroll
        for (int i = 0; i < 8; ++i) {
            float h = v[s][i] * is;
            unsigned short hb = f32_bf16_hi(h);
            ahi[s][i] = (short)hb;
            alo[s][i] = (short)f32_bf16_hi(h - bf16_to_f32(hb));
        }

    // MFMA: this wave computes tiles tg = pairH*2 + t (t=0..1)
    f32x4 accm[2];
#pragma unroll
    for (int t = 0; t < 2; ++t) accm[t] = (f32x4)(0.f);
    const bf16x8* whp = (const bf16x8*)Whi;
    const bf16x8* wlp = (const bf16x8*)Wlo;
#pragma unroll
    for (int s = 0; s < 2; ++s) {
        const int base = (s * 4 + pairH * 2) * 64 + lane;
#pragma unroll
        for (int t = 0; t < 2; ++t) {
            bf16x8 wh = whp[base + t * 64];
            bf16x8 wl = wlp[base + t * 64];
            accm[t] = __builtin_amdgcn_mfma_f32_16x16x32_bf16(ahi[s], wh, accm[t], 0, 0, 0);
            accm[t] = __builtin_amdgcn_mfma_f32_16x16x32_bf16(alo[s], wh, accm[t], 0, 0, 0);
            accm[t] = __builtin_amdgcn_mfma_f32_16x16x32_bf16(ahi[s], wl, accm[t], 0, 0, 0);
        }
    }
#pragma unroll
    for (int r = 0; r < 4; ++r) {
        int row = row0 + q * 4 + r;
        if (row < N) {
            float sc = dinv[row];
#pragma unroll
            for (int t = 0; t < 2; ++t) {
                int c = (pairH * 2 + t) * 16 + m;
                tp16[(size_t)row * 64 + c] = __float2half(accm[t][r] * sc);
            }
        }
    }
}

// ------------------------------ gcn gather ---------------------------------
// half2 lanes: 32 feature-pair lanes x 2 edge-parity groups; combine via
// shfl_xor(32).
__global__ void gcn_agg_kernel(const __half* __restrict__ tp,
                               const int* __restrict__ rowptr, const int* __restrict__ col,
                               const float* __restrict__ dinv, const float* __restrict__ bg,
                               float* __restrict__ out, int N) {
    int node = blockIdx.x * 4 + (threadIdx.x >> 6);
    if (node >= N) return;
    int lane = threadIdx.x & 63;
    int f2 = lane & 31;   // features 2*f2, 2*f2+1
    int ep = lane >> 5;   // edge parity
    int s = rowptr[node], e = rowptr[node + 1];
    float ax[8], ay[8];
#pragma unroll
    for (int k = 0; k < 8; ++k) { ax[k] = 0.f; ay[k] = 0.f; }
    int p = s;
    for (; p + 16 <= e; p += 16) {
#pragma unroll
        for (int k = 0; k < 8; ++k) {
            int j = col[p + 2 * k + ep];
            float2 f = __half22float2(*(const __half2*)(tp + (size_t)j * 64 + 2 * f2));
            ax[k] += f.x;
            ay[k] += f.y;
        }
    }
    for (int t = p + ep; t < e; t += 2) {
        int j = col[t];
        float2 f = __half22float2(*(const __half2*)(tp + (size_t)j * 64 + 2 * f2));
        ax[0] += f.x;
        ay[0] += f.y;
    }
    float sx = ((ax[0] + ax[1]) + (ax[2] + ax[3])) + ((ax[4] + ax[5]) + (ax[6] + ax[7]));
    float sy = ((ay[0] + ay[1]) + (ay[2] + ay[3])) + ((ay[4] + ay[5]) + (ay[6] + ay[7]));
    sx += __shfl_xor(sx, 32, 64);
    sy += __shfl_xor(sy, 32, 64);
    if (ep == 0) {
        float2 selfv = __half22float2(*(const __half2*)(tp + (size_t)node * 64 + 2 * f2));
        float di = dinv[node];
        float2 o;
        o.x = (sx + selfv.x) * di + bg[2 * f2];
        o.y = (sy + selfv.y) * di + bg[2 * f2 + 1];
        *(float2*)(out + (size_t)node * 64 + 2 * f2) = o;
    }
}

extern "C" void kernel_launch(void* const* d_in, const int* in_sizes, int n_in,
                              void* d_out, int out_size, void* d_ws, size_t ws_size,
                              hipStream_t stream) {
    const float* x = (const float*)d_in[0];
    const int* ei = (const int*)d_in[1];    // int32 per harness conversion
    const float* W1l = (const float*)d_in[2];
    const float* b1l = (const float*)d_in[3];
    const float* W1r = (const float*)d_in[4];
    const float* W2l = (const float*)d_in[5];
    const float* b2l = (const float*)d_in[6];
    const float* W2r = (const float*)d_in[7];
    const float* Wg  = (const float*)d_in[8];
    const float* bg  = (const float*)d_in[9];

    const int N = in_sizes[0] / 128;
    const int E = in_sizes[1] / 2;
    const int* srcp = ei;
    const int* dstp = ei + E;

    const int NB = (E + 8191) / 8192;
    const int BK = (N + 255) >> 8;
    const int len = BK * NB;

    // workspace layout
    float* ws = (float*)d_ws;
    float* dinv = ws;                              // N
    unsigned char* p8 = (unsigned char*)(dinv + N);   // N*128 B (fp8)
    __half* q16 = (__half*)(p8 + (size_t)N * 128);    // N*128 half
    unsigned char* r8 = (unsigned char*)(q16 + (size_t)N * 128); // N*64 B (fp8)
    __half* s16 = (__half*)(r8 + (size_t)N * 64);     // N*64 half
    __half* tp16 = s16 + (size_t)N * 64;              // N*64 half
    int* rowptr = (int*)(tp16 + (size_t)N * 64);   // N+1
    int* off    = rowptr + (N + 1);                // len+2
    int* colbuf = off + len + 2;                   // E
    unsigned* ebuf = (unsigned*)(colbuf + E);      // E
    int* bsum   = (int*)(ebuf + E);                // 32
    uintptr_t up = (uintptr_t)(bsum + 32);
    up = (up + 15) & ~(uintptr_t)15;
    unsigned short* p1h = (unsigned short*)up;     // 32768 (128x256)
    unsigned short* p1l = p1h + 32768;
    unsigned short* p2h = p1l + 32768;             // 16384 (128x128)
    unsigned short* p2l = p2h + 16384;
    unsigned short* p3h = p2l + 16384;             // 4096 (64x64)
    unsigned short* p3l = p3h + 4096;

    float* out = (float*)d_out;

    // --- CSR build (radix by dst), packw fused into count dispatch ---
    count_packw_kernel<<<NB + 320, 256, 0, stream>>>(dstp, off, E, NB, BK,
                                                     W1l, W1r, W2l, W2r, Wg,
                                                     p1h, p1l, p2h, p2l, p3h, p3l);
    const int sn = len + 1;
    const int SBs = (sn + 2047) / 2048;
    scan_reduce_kernel<<<SBs, 256, 0, stream>>>(off, bsum, sn);
    scan_final_kernel<<<SBs, 256, 0, stream>>>(off, bsum, sn);
    partition_kernel<<<NB, 256, 0, stream>>>(srcp, dstp, off, ebuf, E, NB, BK);
    finalize_kernel<<<BK, 256, 0, stream>>>(ebuf, off, colbuf, rowptr, dinv, N, NB, E);

    const int gb  = (N + 63) / 64;   // gemm1
    const int gbf = (N + 31) / 32;   // fused (pair-split)
    const int ab  = (N + 3) / 4;     // gcn_agg

    // gemm1: y=0 -> p8 (fp8, lane-packed), y=1 -> q16 (fp16)
    gemm1_kernel<<<dim3(gb, 2), 256, 0, stream>>>(x, p1h, p1l, p8, q16, N);

    // fused: h1 = relu(mean(p8)+q16+b1l); [r8|s16] = h1 @ [W2l|W2r]
    sage2_fused_kernel<<<gbf, 256, 0, stream>>>(p8, q16, rowptr, colbuf, b1l,
                                                p2h, p2l, r8, s16, N);

    // fused: h2 = softmax(mean(r8)+s16+b2l); tp16 = (h2 @ Wg) * dinv
    gcn_prep_fused_kernel<<<gbf, 256, 0, stream>>>(r8, s16, rowptr, colbuf, b2l,
                                                   p3h, p3l, dinv, tp16, N);

    gcn_agg_kernel<<<ab, 256, 0, stream>>>(tp16, rowptr, colbuf, dinv, bg, out, N);
}